// Round 7
// baseline (60.289 us; speedup 1.0000x reference)
//
#include <hip/hip_runtime.h>
#include <math.h>

#define NEG 0.2f
#define GROUPS 8192

typedef unsigned short u16;
typedef u16 ushort8 __attribute__((ext_vector_type(8)));
typedef short s16x8 __attribute__((ext_vector_type(8)));
typedef float f32x4 __attribute__((ext_vector_type(4)));

__device__ __forceinline__ float lrelu(float x){ return x >= 0.f ? x : NEG*x; }
__device__ __forceinline__ float eluf(float x){ return x > 0.f ? x : __expf(x) - 1.f; }
__device__ __forceinline__ int eidx(int s,int d){ return s*7 + (d<s ? d : d-1); }
__device__ __forceinline__ float bf2f(u16 u){
    union { unsigned i; float f; } v; v.i = ((unsigned)u)<<16; return v.f;
}
__device__ __forceinline__ u16 f2bf(float f){
    union { float f; unsigned i; } v; v.f = f;
    unsigned r = v.i + 0x7fffu + ((v.i>>16)&1u);
    return (u16)(r>>16);
}

// ---------------------------------------------------------------------------
// prep: bf16 MFMA B-fragments for W2 (32), Wr1 (16), Wr2 (20, N 72->80),
// Wc1 (4); W1s table (attention vectors folded into x-space); ce scalars.
// Fragment f (1 KB): lane l holds B[k0 + (l>>4)*8 + j][c0 + (l&15)], j=0..7.
// ---------------------------------------------------------------------------
__global__ __launch_bounds__(64)
void prep(const float* __restrict__ W1, const float* __restrict__ a_src1,
          const float* __restrict__ a_dst1, const float* __restrict__ W2,
          const float* __restrict__ Wr1, const float* __restrict__ Wr2,
          const float* __restrict__ Wc1,
          const float* __restrict__ We1, const float* __restrict__ a_e1,
          const float* __restrict__ We2, const float* __restrict__ a_e2,
          u16* __restrict__ wfrag, u16* __restrict__ wr1f,
          u16* __restrict__ wr2f, u16* __restrict__ wc1f,
          float* __restrict__ w1s, float* __restrict__ ces)
{
    const int b = blockIdx.x, l = threadIdx.x;
    const int c0 = l & 15, o = l >> 4;
    if (b < 32) {                       // W2: 256x64, f = t*8+s
        const int t = b >> 3, s = b & 7;
        ushort8 p;
#pragma unroll
        for (int j = 0; j < 8; ++j) p[j] = f2bf(W2[(s*32 + o*8 + j)*64 + t*16 + c0]);
        *(ushort8*)(wfrag + (size_t)(b*64 + l)*8) = p;
    } else if (b < 48) {                // Wr1: 64x128, f = ks*8+t
        const int f = b - 32, ks = f >> 3, t = f & 7;
        ushort8 p;
#pragma unroll
        for (int j = 0; j < 8; ++j) p[j] = f2bf(Wr1[(ks*32 + o*8 + j)*128 + t*16 + c0]);
        *(ushort8*)(wr1f + (size_t)(f*64 + l)*8) = p;
    } else if (b < 68) {                // Wr2: 128x72 (pad N->80), f = ks*5+t
        const int f = b - 48, ks = f / 5, t = f % 5;
        const int c = t*16 + c0;
        ushort8 p;
#pragma unroll
        for (int j = 0; j < 8; ++j)
            p[j] = (c < 72) ? f2bf(Wr2[(ks*32 + o*8 + j)*72 + c]) : (u16)0;
        *(ushort8*)(wr2f + (size_t)(f*64 + l)*8) = p;
    } else if (b < 72) {                // Wc1: 64x32, f = ks*2+t
        const int f = b - 68, ks = f >> 1, t = f & 1;
        ushort8 p;
#pragma unroll
        for (int j = 0; j < 8; ++j) p[j] = f2bf(Wc1[(ks*32 + o*8 + j)*32 + t*16 + c0]);
        *(ushort8*)(wc1f + (size_t)(f*64 + l)*8) = p;
    } else if (b == 72) {               // W1s[k][cc]: cc<4 -> src h=cc, cc>=4 -> dst
        for (int idx = l; idx < 72; idx += 64) {
            const int k = idx >> 3, cc = idx & 7, h = cc & 3;
            const float* av = (cc < 4) ? a_src1 : a_dst1;
            float acc = 0.f;
#pragma unroll 8
            for (int i = 0; i < 64; ++i) acc = fmaf(W1[k*256 + h*64 + i], av[h*64 + i], acc);
            w1s[idx] = acc;
        }
    } else {                            // ce scalars
        if (l < 4) {
            float c = 0.f;
#pragma unroll 8
            for (int i = 0; i < 64; ++i) c = fmaf(We1[l*64+i], a_e1[l*64+i], c);
            ces[l] = c;
        } else if (l == 4) {
            float c = 0.f;
#pragma unroll 8
            for (int i = 0; i < 64; ++i) c = fmaf(We2[i], a_e2[i], c);
            ces[4] = c;
        }
    }
}

// ---------------------------------------------------------------------------
// One wave (64 threads) per block, 2 groups per wave.
// lane = n*8 + cg  (n: node 0..7, cg: channel-group 0..7)
// LDS = 10240 B exactly -> 16 blocks/CU -> entire 4096-block grid co-resident
// (no second residency round / tail). __syncthreads + launch_bounds(64,4)
// reproduce round-4's spill-free codegen (108 VGPR).
// ---------------------------------------------------------------------------
__global__ __launch_bounds__(64, 4)
void gat_fused7(const float* __restrict__ x, const float* __restrict__ ew_g,
    const float* __restrict__ W1, const float* __restrict__ b1,
    const float* __restrict__ a_src2, const float* __restrict__ a_dst2,
    const float* __restrict__ b2,
    const float* __restrict__ br1, const float* __restrict__ br2,
    const float* __restrict__ bc1, const float* __restrict__ Wc2,
    const float* __restrict__ bc2,
    const u16* __restrict__ wfrag, const u16* __restrict__ wr1f,
    const u16* __restrict__ wr2f, const u16* __restrict__ wc1f,
    const float* __restrict__ w1s, const float* __restrict__ cesg,
    float* __restrict__ recon, float* __restrict__ cls)
{
    // 8448 + 1024 + 256 + 448 + 64 = 10240 B
    __shared__ __align__(16) u16 act[2][8][264];      // bf16 xp1 -> h1; f32 xp2 overlay
    __shared__ __align__(16) u16 alpha1b[2][4][8][8]; // bf16 [g][head][dst][src]; emb/r1 overlay later
    __shared__ __align__(16) u16 alpha2b[2][8][8];    // bf16 [g][dst][src]
    __shared__ float ews2[2][56];
    __shared__ float lws[2][8];

    // overlays on alpha1b (dead after S4): embs16 [2][64], r1s16 [2][128] (768 of 1024 B)
    u16* const embs16 = (u16*)alpha1b;          // 256 B
    u16* const r1s16  = (u16*)alpha1b + 128;    // 512 B

    const int lane = threadIdx.x;       // 0..63
    const int n    = lane >> 3;
    const int cg   = lane & 7;
    const int g0   = blockIdx.x * 2;

    // --- stage edge weights (cooperative); x goes straight to registers ---
    {
        const float* eg = ew_g + (size_t)g0 * 56;
        for (int i = lane; i < 112; i += 64) (&ews2[0][0])[i] = eg[i];
    }

    // --- per-lane x rows for S1 (row n, both groups) ---
    float xr0[9], xr1[9];
    {
        const float* p0 = x + (size_t)g0 * 72 + n * 9;
        const float* p1 = p0 + 72;
#pragma unroll
        for (int k = 0; k < 9; ++k) { xr0[k] = p0[k]; xr1[k] = p1[k]; }
    }

    // --- S2': attention logits al_s/al_d straight from x via w1s (registers) ---
    // lane -> (gg = lane>>5, nn = (lane>>2)&7, hh = lane&3); ald is lane-local.
    float alsv = 0.f, aldv = 0.f;
    {
        const int gg = lane >> 5, nn = (lane >> 2) & 7, hh = lane & 3;
        const float* xs = x + (size_t)(g0 + gg) * 72 + nn * 9;
#pragma unroll
        for (int k = 0; k < 9; ++k) {
            const float xv = xs[k];
            alsv = fmaf(xv, w1s[k*8 + hh], alsv);
            aldv = fmaf(xv, w1s[k*8 + 4 + hh], aldv);
        }
    }

    __syncthreads();   // ews2 staged

    // self-loop attr = mean of 7 incoming edge weights
    if (lane < 16) {
        const int g = lane >> 3, d = lane & 7;
        float s = 0.f;
#pragma unroll
        for (int ss = 0; ss < 8; ++ss) if (ss != d) s += ews2[g][eidx(ss, d)];
        lws[g][d] = s * (1.f/7.f);
    }

    // --- S1: xp1 = x @ W1 for both groups; lane owns cols {u*64 + cg*8 + 0..7} ---
    {
#pragma unroll
        for (int u = 0; u < 4; ++u) {
            const int cb = u*64 + cg*8;
            float a0[8] = {0,0,0,0,0,0,0,0}, a1[8] = {0,0,0,0,0,0,0,0};
#pragma unroll
            for (int k = 0; k < 9; ++k) {
                const float4 w0 = *(const float4*)(W1 + k*256 + cb);
                const float4 w1 = *(const float4*)(W1 + k*256 + cb + 4);
                const float f0 = xr0[k], f1 = xr1[k];
                a0[0]=fmaf(f0,w0.x,a0[0]); a0[1]=fmaf(f0,w0.y,a0[1]);
                a0[2]=fmaf(f0,w0.z,a0[2]); a0[3]=fmaf(f0,w0.w,a0[3]);
                a0[4]=fmaf(f0,w1.x,a0[4]); a0[5]=fmaf(f0,w1.y,a0[5]);
                a0[6]=fmaf(f0,w1.z,a0[6]); a0[7]=fmaf(f0,w1.w,a0[7]);
                a1[0]=fmaf(f1,w0.x,a1[0]); a1[1]=fmaf(f1,w0.y,a1[1]);
                a1[2]=fmaf(f1,w0.z,a1[2]); a1[3]=fmaf(f1,w0.w,a1[3]);
                a1[4]=fmaf(f1,w1.x,a1[4]); a1[5]=fmaf(f1,w1.y,a1[5]);
                a1[6]=fmaf(f1,w1.z,a1[6]); a1[7]=fmaf(f1,w1.w,a1[7]);
            }
            ushort8 p0, p1;
#pragma unroll
            for (int j = 0; j < 8; ++j) { p0[j] = f2bf(a0[j]); p1[j] = f2bf(a1[j]); }
            *(ushort8*)&act[0][n][cb] = p0;
            *(ushort8*)&act[1][n][cb] = p1;
        }
    }

    __syncthreads();   // act(xp1), lws visible

    // --- S3: softmax layer1; lane -> (g, dst, h); als via shfl (same mapping) ---
    {
        const int gg = lane >> 5, dd = (lane >> 2) & 7, hh = lane & 3;
        const float ce = cesg[hh];
        const float ad = aldv;   // lane-local by construction
        float lg[8], mx = -1e30f;
#pragma unroll
        for (int ss = 0; ss < 8; ++ss) {
            const float as_ = __shfl(alsv, (lane & 0x23) | (ss << 2));
            const float w = (ss == dd) ? lws[gg][dd] : ews2[gg][eidx(ss, dd)];
            float t = as_ + ad + ce * w;
            t = lrelu(t);
            lg[ss] = t; mx = fmaxf(mx, t);
        }
        float sum = 0.f;
#pragma unroll
        for (int ss = 0; ss < 8; ++ss) { lg[ss] = __expf(lg[ss] - mx); sum += lg[ss]; }
        const float inv = 1.f / (sum + 1e-16f);
        ushort8 ap;
#pragma unroll
        for (int ss = 0; ss < 8; ++ss) ap[ss] = f2bf(lg[ss] * inv);
        *(ushort8*)&alpha1b[gg][hh][dd][0] = ap;
    }

    __syncthreads();   // alpha1 visible

    // --- S4: h1 = ELU(alpha @ xp1 + b1), written back as bf16 (per group) ---
    for (int g = 0; g < 2; ++g) {
        float hv[32];
#pragma unroll
        for (int u = 0; u < 4; ++u) {
            const ushort8 al8 = *(const ushort8*)&alpha1b[g][u][n][0];
            float acc[8] = {0,0,0,0,0,0,0,0};
#pragma unroll
            for (int s = 0; s < 8; ++s) {
                const float av = bf2f(al8[s]);
                const ushort8 v = *(const ushort8*)&act[g][s][u*64 + cg*8];
#pragma unroll
                for (int j = 0; j < 8; ++j) acc[j] = fmaf(av, bf2f(v[j]), acc[j]);
            }
#pragma unroll
            for (int j = 0; j < 8; ++j) hv[u*8+j] = acc[j];
        }
        __syncthreads();   // all reads of act[g] done before overwrite
#pragma unroll
        for (int u = 0; u < 4; ++u) {
            const int cb = u*64 + cg*8;
            const float4 b0 = *(const float4*)(b1 + cb);
            const float4 b2v = *(const float4*)(b1 + cb + 4);
            ushort8 p;
            p[0]=f2bf(eluf(hv[u*8+0]+b0.x)); p[1]=f2bf(eluf(hv[u*8+1]+b0.y));
            p[2]=f2bf(eluf(hv[u*8+2]+b0.z)); p[3]=f2bf(eluf(hv[u*8+3]+b0.w));
            p[4]=f2bf(eluf(hv[u*8+4]+b2v.x)); p[5]=f2bf(eluf(hv[u*8+5]+b2v.y));
            p[6]=f2bf(eluf(hv[u*8+6]+b2v.z)); p[7]=f2bf(eluf(hv[u*8+7]+b2v.w));
            *(ushort8*)&act[g][n][cb] = p;
        }
        __syncthreads();
    }

    // --- GEMM2 via MFMA: xp2[16][64] = h1[16][256] @ W2 ---
    f32x4 acc[4] = {{0,0,0,0},{0,0,0,0},{0,0,0,0},{0,0,0,0}};
    {
        const int r = lane & 15;
        const u16* arow = &act[r >> 3][r & 7][(lane >> 4) * 8];
#pragma unroll
        for (int s = 0; s < 8; ++s) {
            const s16x8 af = *(const s16x8*)(arow + s * 32);
#pragma unroll
            for (int t = 0; t < 4; ++t) {
                const s16x8 bf = *(const s16x8*)(wfrag + (size_t)(((t*8 + s)*64 + lane))*8);
                acc[t] = __builtin_amdgcn_mfma_f32_16x16x32_bf16(af, bf, acc[t], 0, 0, 0);
            }
        }
    }

    // --- al_s2 / al_d2 dots + 16-lane butterfly (rows (lane>>4)*4+i in registers) ---
    float sp[4] = {0,0,0,0}, dp[4] = {0,0,0,0};
    {
        const int c0 = lane & 15;
#pragma unroll
        for (int t = 0; t < 4; ++t) {
            const float as_ = a_src2[t*16 + c0];
            const float ad_ = a_dst2[t*16 + c0];
#pragma unroll
            for (int i = 0; i < 4; ++i) {
                sp[i] = fmaf(acc[t][i], as_, sp[i]);
                dp[i] = fmaf(acc[t][i], ad_, dp[i]);
            }
        }
#pragma unroll
        for (int i = 0; i < 4; ++i) {
            sp[i] += __shfl_xor(sp[i],1); sp[i] += __shfl_xor(sp[i],2);
            sp[i] += __shfl_xor(sp[i],4); sp[i] += __shfl_xor(sp[i],8);
            dp[i] += __shfl_xor(dp[i],1); dp[i] += __shfl_xor(dp[i],2);
            dp[i] += __shfl_xor(dp[i],4); dp[i] += __shfl_xor(dp[i],8);
        }
    }

    // --- softmax layer2 via shfl (no LDS als2/ald2); all lanes compute, <16 store ---
    {
        const int g = (lane >> 3) & 1, d = lane & 7;
        // als2[g][ss]: row r=g*8+ss lives in lane-group o=g*2+(ss>>2), reg i=ss&3
        float al[8];
#pragma unroll
        for (int ss = 0; ss < 8; ++ss)
            al[ss] = __shfl(sp[ss & 3], (g*2 + (ss >> 2)) * 16);
        const int srcd = (g*2 + (d >> 2)) * 16;
        const float q0 = __shfl(dp[0], srcd), q1 = __shfl(dp[1], srcd);
        const float q2 = __shfl(dp[2], srcd), q3 = __shfl(dp[3], srcd);
        const float ad = (d & 2) ? ((d & 1) ? q3 : q2) : ((d & 1) ? q1 : q0);
        const float ce = cesg[4];
        float lg[8], mx = -1e30f;
#pragma unroll
        for (int ss = 0; ss < 8; ++ss) {
            const float w = (ss == d) ? lws[g][d] : ews2[g][eidx(ss, d)];
            float t = al[ss] + ad + ce * w;
            t = lrelu(t);
            lg[ss] = t; mx = fmaxf(mx, t);
        }
        float sum = 0.f;
#pragma unroll
        for (int ss = 0; ss < 8; ++ss) { lg[ss] = __expf(lg[ss] - mx); sum += lg[ss]; }
        const float inv = 1.f / (sum + 1e-16f);
        if (lane < 16) {
            ushort8 ap;
#pragma unroll
            for (int ss = 0; ss < 8; ++ss) ap[ss] = f2bf(lg[ss] * inv);
            *(ushort8*)&alpha2b[g][d][0] = ap;
        }
    }
    __syncthreads();   // GEMM2 act reads complete before xp2 overlay

    // --- store xp2 (f32) overlaid on act region, row stride 68 floats ---
    float* xf0 = reinterpret_cast<float*>(&act[0][0][0]);
    float* xf1 = reinterpret_cast<float*>(&act[1][0][0]);
    {
        const int c0 = lane & 15;
#pragma unroll
        for (int t = 0; t < 4; ++t)
#pragma unroll
            for (int i = 0; i < 4; ++i) {
                const int r = (lane >> 4)*4 + i;
                float* xf = (r >> 3) ? xf1 : xf0;
                xf[(r & 7)*68 + t*16 + c0] = acc[t][i];
            }
    }
    __syncthreads();   // xp2 + alpha2b visible

    // --- aggregate2 + b2 + ELU + mean-pool -> embs16 (bf16) ---
    float h2[2][8];
#pragma unroll
    for (int g = 0; g < 2; ++g) {
        const float* xf = g ? xf1 : xf0;
        const ushort8 a2 = *(const ushort8*)&alpha2b[g][n][0];
        float a[8] = {0,0,0,0,0,0,0,0};
#pragma unroll
        for (int ss = 0; ss < 8; ++ss) {
            const float av = bf2f(a2[ss]);
            const float4 v0 = *(const float4*)(xf + ss*68 + cg*8);
            const float4 v1 = *(const float4*)(xf + ss*68 + cg*8 + 4);
            a[0]=fmaf(av,v0.x,a[0]); a[1]=fmaf(av,v0.y,a[1]);
            a[2]=fmaf(av,v0.z,a[2]); a[3]=fmaf(av,v0.w,a[3]);
            a[4]=fmaf(av,v1.x,a[4]); a[5]=fmaf(av,v1.y,a[5]);
            a[6]=fmaf(av,v1.z,a[6]); a[7]=fmaf(av,v1.w,a[7]);
        }
        const float4 b0 = *(const float4*)(b2 + cg*8);
        const float4 b1v = *(const float4*)(b2 + cg*8 + 4);
        h2[g][0]=eluf(a[0]+b0.x); h2[g][1]=eluf(a[1]+b0.y);
        h2[g][2]=eluf(a[2]+b0.z); h2[g][3]=eluf(a[3]+b0.w);
        h2[g][4]=eluf(a[4]+b1v.x); h2[g][5]=eluf(a[5]+b1v.y);
        h2[g][6]=eluf(a[6]+b1v.z); h2[g][7]=eluf(a[7]+b1v.w);
    }
#pragma unroll
    for (int g = 0; g < 2; ++g)
#pragma unroll
        for (int j = 0; j < 8; ++j) {
            float v = h2[g][j];
            v += __shfl_xor(v, 8); v += __shfl_xor(v, 16); v += __shfl_xor(v, 32);
            h2[g][j] = v * 0.125f;
        }
    __syncthreads();   // aggregate2's alpha1b-overlay region now dead (S4 done long ago)
    if (n == 0) {       // lane < 8, cg = lane
#pragma unroll
        for (int g = 0; g < 2; ++g) {
            ushort8 p;
#pragma unroll
            for (int j = 0; j < 8; ++j) p[j] = f2bf(h2[g][j]);
            *(ushort8*)&embs16[g*64 + lane*8] = p;
        }
    }
    __syncthreads();   // embs16 visible

    // --- readout via MFMA (M=2 rows used of 16) ---
    s16x8 aemb0 = {0,0,0,0,0,0,0,0}, aemb1 = {0,0,0,0,0,0,0,0};
    {
        const int r = lane & 15, o = lane >> 4;
        if (r < 2) {
            aemb0 = *(const s16x8*)&embs16[r*64 + o*8];
            aemb1 = *(const s16x8*)&embs16[r*64 + 32 + o*8];
        }
    }
    // r1 = relu(emb @ Wr1 + br1) -> r1s16 (bf16)
    {
        f32x4 ar[8];
        const f32x4 z = {0,0,0,0};
#pragma unroll
        for (int t = 0; t < 8; ++t) ar[t] = z;
#pragma unroll
        for (int t = 0; t < 8; ++t) {
            ar[t] = __builtin_amdgcn_mfma_f32_16x16x32_bf16(
                aemb0, *(const s16x8*)(wr1f + (size_t)((0*8 + t)*64 + lane)*8), ar[t], 0,0,0);
            ar[t] = __builtin_amdgcn_mfma_f32_16x16x32_bf16(
                aemb1, *(const s16x8*)(wr1f + (size_t)((1*8 + t)*64 + lane)*8), ar[t], 0,0,0);
        }
        const int c0 = lane & 15, o = lane >> 4;
        if (o == 0) {
#pragma unroll
            for (int t = 0; t < 8; ++t) {
                const float bb = br1[t*16 + c0];
                r1s16[0*128 + t*16 + c0] = f2bf(fmaxf(ar[t][0] + bb, 0.f));
                r1s16[1*128 + t*16 + c0] = f2bf(fmaxf(ar[t][1] + bb, 0.f));
            }
        }
    }
    __syncthreads();

    // recon = r1 @ Wr2 + br2  (direct global store)
    {
        f32x4 ac[5];
        const f32x4 z = {0,0,0,0};
#pragma unroll
        for (int t = 0; t < 5; ++t) ac[t] = z;
        const int r = lane & 15, o = lane >> 4;
#pragma unroll
        for (int ks = 0; ks < 4; ++ks) {
            s16x8 a = {0,0,0,0,0,0,0,0};
            if (r < 2) a = *(const s16x8*)&r1s16[r*128 + ks*32 + o*8];
#pragma unroll
            for (int t = 0; t < 5; ++t)
                ac[t] = __builtin_amdgcn_mfma_f32_16x16x32_bf16(
                    a, *(const s16x8*)(wr2f + (size_t)((ks*5 + t)*64 + lane)*8), ac[t], 0,0,0);
        }
        if (o == 0) {
            const int c0 = r;
#pragma unroll
            for (int t = 0; t < 5; ++t) {
                const int c = t*16 + c0;
                if (c < 72) {
                    const float bb = br2[c];
                    recon[(size_t)g0*72 + c]       = ac[t][0] + bb;
                    recon[(size_t)(g0+1)*72 + c]   = ac[t][1] + bb;
                }
            }
        }
    }

    // cls = relu(emb @ Wc1 + bc1) @ Wc2 + bc2
    {
        f32x4 ac[2];
        const f32x4 z = {0,0,0,0};
        ac[0] = z; ac[1] = z;
#pragma unroll
        for (int t = 0; t < 2; ++t) {
            ac[t] = __builtin_amdgcn_mfma_f32_16x16x32_bf16(
                aemb0, *(const s16x8*)(wc1f + (size_t)((0*2 + t)*64 + lane)*8), ac[t], 0,0,0);
            ac[t] = __builtin_amdgcn_mfma_f32_16x16x32_bf16(
                aemb1, *(const s16x8*)(wc1f + (size_t)((1*2 + t)*64 + lane)*8), ac[t], 0,0,0);
        }
        const int c0 = lane & 15;
        const float bb0 = bc1[c0], bb1 = bc1[16 + c0];
        const float wc0 = Wc2[c0], wc1v = Wc2[16 + c0];
        float p0 = fmaxf(ac[0][0] + bb0, 0.f)*wc0 + fmaxf(ac[1][0] + bb1, 0.f)*wc1v;
        float p1 = fmaxf(ac[0][1] + bb0, 0.f)*wc0 + fmaxf(ac[1][1] + bb1, 0.f)*wc1v;
        p0 += __shfl_xor(p0,1); p0 += __shfl_xor(p0,2); p0 += __shfl_xor(p0,4); p0 += __shfl_xor(p0,8);
        p1 += __shfl_xor(p1,1); p1 += __shfl_xor(p1,2); p1 += __shfl_xor(p1,4); p1 += __shfl_xor(p1,8);
        if (lane == 0) { cls[g0] = p0 + bc2[0]; cls[g0+1] = p1 + bc2[0]; }
    }
}

extern "C" void kernel_launch(void* const* d_in, const int* in_sizes, int n_in,
                              void* d_out, int out_size, void* d_ws, size_t ws_size,
                              hipStream_t stream) {
    const float* x      = (const float*)d_in[0];
    const float* ew     = (const float*)d_in[2];
    const float* W1     = (const float*)d_in[4];
    const float* a_src1 = (const float*)d_in[5];
    const float* a_dst1 = (const float*)d_in[6];
    const float* We1    = (const float*)d_in[7];
    const float* a_e1   = (const float*)d_in[8];
    const float* b1     = (const float*)d_in[9];
    const float* W2     = (const float*)d_in[10];
    const float* a_src2 = (const float*)d_in[11];
    const float* a_dst2 = (const float*)d_in[12];
    const float* We2    = (const float*)d_in[13];
    const float* a_e2   = (const float*)d_in[14];
    const float* b2     = (const float*)d_in[15];
    const float* Wr1    = (const float*)d_in[16];
    const float* br1    = (const float*)d_in[17];
    const float* Wr2    = (const float*)d_in[18];
    const float* br2    = (const float*)d_in[19];
    const float* Wc1    = (const float*)d_in[20];
    const float* bc1    = (const float*)d_in[21];
    const float* Wc2    = (const float*)d_in[22];
    const float* bc2    = (const float*)d_in[23];

    float* recon = (float*)d_out;
    float* cls   = (float*)d_out + (size_t)GROUPS * 72;

    char* ws = (char*)d_ws;
    u16*   wfrag = (u16*)(ws + 0);          // 32 KB
    u16*   wr1f  = (u16*)(ws + 32768);      // 16 KB
    u16*   wr2f  = (u16*)(ws + 49152);      // 20 KB
    u16*   wc1f  = (u16*)(ws + 69632);      // 4 KB
    float* w1s   = (float*)(ws + 73728);    // 288 B
    float* ces   = (float*)(ws + 74016);    // 24 B

    hipLaunchKernelGGL(prep, dim3(74), dim3(64), 0, stream,
                       W1, a_src1, a_dst1, W2, Wr1, Wr2, Wc1,
                       We1, a_e1, We2, a_e2,
                       wfrag, wr1f, wr2f, wc1f, w1s, ces);

    hipLaunchKernelGGL(gat_fused7, dim3(GROUPS/2), dim3(64), 0, stream,
                       x, ew, W1, b1, a_src2, a_dst2, b2,
                       br1, br2, bc1, Wc2, bc2,
                       wfrag, wr1f, wr2f, wc1f, w1s, ces,
                       recon, cls);
}

// Round 8
// 52.832 us; speedup vs baseline: 1.1411x; 1.1411x over previous
//
#include <hip/hip_runtime.h>
#include <math.h>

#define NEG 0.2f
#define GROUPS 8192

typedef unsigned short u16;
typedef u16 ushort8 __attribute__((ext_vector_type(8)));
typedef short s16x8 __attribute__((ext_vector_type(8)));
typedef float f32x4 __attribute__((ext_vector_type(4)));

__device__ __forceinline__ float lrelu(float x){ return x >= 0.f ? x : NEG*x; }
__device__ __forceinline__ float eluf(float x){ return x > 0.f ? x : __expf(x) - 1.f; }
__device__ __forceinline__ int eidx(int s,int d){ return s*7 + (d<s ? d : d-1); }
__device__ __forceinline__ float bf2f(u16 u){
    union { unsigned i; float f; } v; v.i = ((unsigned)u)<<16; return v.f;
}
__device__ __forceinline__ u16 f2bf(float f){
    union { float f; unsigned i; } v; v.f = f;
    unsigned r = v.i + 0x7fffu + ((v.i>>16)&1u);
    return (u16)(r>>16);
}

// ---------------------------------------------------------------------------
// prep: bf16 MFMA B-fragments for W2 (32), Wr1 (16), Wr2 (20, N 72->80),
// Wc1 (4); W1s table (attention vectors folded into x-space); ce scalars.
// Fragment f (1 KB): lane l holds B[k0 + (l>>4)*8 + j][c0 + (l&15)], j=0..7.
// ---------------------------------------------------------------------------
__global__ __launch_bounds__(64)
void prep(const float* __restrict__ W1, const float* __restrict__ a_src1,
          const float* __restrict__ a_dst1, const float* __restrict__ W2,
          const float* __restrict__ Wr1, const float* __restrict__ Wr2,
          const float* __restrict__ Wc1,
          const float* __restrict__ We1, const float* __restrict__ a_e1,
          const float* __restrict__ We2, const float* __restrict__ a_e2,
          u16* __restrict__ wfrag, u16* __restrict__ wr1f,
          u16* __restrict__ wr2f, u16* __restrict__ wc1f,
          float* __restrict__ w1s, float* __restrict__ ces)
{
    const int b = blockIdx.x, l = threadIdx.x;
    const int c0 = l & 15, o = l >> 4;
    if (b < 32) {                       // W2: 256x64, f = t*8+s
        const int t = b >> 3, s = b & 7;
        ushort8 p;
#pragma unroll
        for (int j = 0; j < 8; ++j) p[j] = f2bf(W2[(s*32 + o*8 + j)*64 + t*16 + c0]);
        *(ushort8*)(wfrag + (size_t)(b*64 + l)*8) = p;
    } else if (b < 48) {                // Wr1: 64x128, f = ks*8+t
        const int f = b - 32, ks = f >> 3, t = f & 7;
        ushort8 p;
#pragma unroll
        for (int j = 0; j < 8; ++j) p[j] = f2bf(Wr1[(ks*32 + o*8 + j)*128 + t*16 + c0]);
        *(ushort8*)(wr1f + (size_t)(f*64 + l)*8) = p;
    } else if (b < 68) {                // Wr2: 128x72 (pad N->80), f = ks*5+t
        const int f = b - 48, ks = f / 5, t = f % 5;
        const int c = t*16 + c0;
        ushort8 p;
#pragma unroll
        for (int j = 0; j < 8; ++j)
            p[j] = (c < 72) ? f2bf(Wr2[(ks*32 + o*8 + j)*72 + c]) : (u16)0;
        *(ushort8*)(wr2f + (size_t)(f*64 + l)*8) = p;
    } else if (b < 72) {                // Wc1: 64x32, f = ks*2+t
        const int f = b - 68, ks = f >> 1, t = f & 1;
        ushort8 p;
#pragma unroll
        for (int j = 0; j < 8; ++j) p[j] = f2bf(Wc1[(ks*32 + o*8 + j)*32 + t*16 + c0]);
        *(ushort8*)(wc1f + (size_t)(f*64 + l)*8) = p;
    } else if (b == 72) {               // W1s[k][cc]: cc<4 -> src h=cc, cc>=4 -> dst
        for (int idx = l; idx < 72; idx += 64) {
            const int k = idx >> 3, cc = idx & 7, h = cc & 3;
            const float* av = (cc < 4) ? a_src1 : a_dst1;
            float acc = 0.f;
#pragma unroll 8
            for (int i = 0; i < 64; ++i) acc = fmaf(W1[k*256 + h*64 + i], av[h*64 + i], acc);
            w1s[idx] = acc;
        }
    } else {                            // ce scalars
        if (l < 4) {
            float c = 0.f;
#pragma unroll 8
            for (int i = 0; i < 64; ++i) c = fmaf(We1[l*64+i], a_e1[l*64+i], c);
            ces[l] = c;
        } else if (l == 4) {
            float c = 0.f;
#pragma unroll 8
            for (int i = 0; i < 64; ++i) c = fmaf(We2[i], a_e2[i], c);
            ces[4] = c;
        }
    }
}

// ---------------------------------------------------------------------------
// One wave per block, 2 groups per wave. lane = n*8 + cg.
// Key algebra: out1 = alpha @ (x @ W1) = (alpha @ x) @ W1, so xp1 is never
// materialized: y = alpha@x (per head, 8x9) is computed per-lane from xw,
// and h1 = ELU(y@W1 + b1) is produced DIRECTLY in MFMA A-fragment layout
// in registers (lane holds row lane&15, k-octet lane>>4). No act[] buffer,
// no xp1 quantization, no S4 LDS reads. LDS ~8.7 KB -> 18 blocks/CU
// (whole 4096-block grid co-resident at 16/CU).
// r4-style codegen: real __shared__ arrays only, no overlays, __syncthreads.
// ---------------------------------------------------------------------------
__global__ __launch_bounds__(64, 4)
void gat_fused8(const float* __restrict__ x, const float* __restrict__ ew_g,
    const float* __restrict__ W1, const float* __restrict__ b1,
    const float* __restrict__ a_src2, const float* __restrict__ a_dst2,
    const float* __restrict__ b2,
    const float* __restrict__ br1, const float* __restrict__ br2,
    const float* __restrict__ bc1, const float* __restrict__ Wc2,
    const float* __restrict__ bc2,
    const u16* __restrict__ wfrag, const u16* __restrict__ wr1f,
    const u16* __restrict__ wr2f, const u16* __restrict__ wc1f,
    const float* __restrict__ w1s, const float* __restrict__ cesg,
    float* __restrict__ recon, float* __restrict__ cls)
{
    __shared__ __align__(16) float xw[2][72];
    __shared__ float ews2[2][56];
    __shared__ float lws[2][8];
    __shared__ float w1sL[72];
    __shared__ float cesL[6];
    __shared__ __align__(16) u16 alpha1b[2][4][8][8];   // bf16 [g][h][dst][src]
    __shared__ float als1[64], ald1[64];                // idx = g*32 + n*4 + h
    __shared__ float als2[2][8], ald2[2][8];
    __shared__ float alpha2[2][8][8];
    __shared__ __align__(16) float xp2f[2][8][68];      // xp2, stride 68
    __shared__ __align__(16) u16 embs16[2][64];
    __shared__ __align__(16) u16 r1s16[2][128];

    const int lane = threadIdx.x;       // 0..63
    const int n    = lane >> 3;
    const int cg   = lane & 7;
    const int g0   = blockIdx.x * 2;
    const int o    = lane >> 4;         // k-octet (MFMA A)
    const int rr   = lane & 15;         // A row
    const int gA   = rr >> 3, nA = rr & 7;

    // --- stage x (2x72), edge weights (2x56), w1s, ces ---
    {
        const float* xg = x + (size_t)g0 * 72;
        for (int i = lane; i < 144; i += 64) (&xw[0][0])[i] = xg[i];
        const float* eg = ew_g + (size_t)g0 * 56;
        for (int i = lane; i < 112; i += 64) (&ews2[0][0])[i] = eg[i];
        for (int i = lane; i < 72; i += 64) w1sL[i] = w1s[i];
        if (lane < 6) cesL[lane] = cesg[lane];
    }
    __syncthreads();   // B1

    // self-loop attr = mean of 7 incoming edge weights
    if (lane < 16) {
        const int g = lane >> 3, d = lane & 7;
        float s = 0.f;
#pragma unroll
        for (int ss = 0; ss < 8; ++ss) if (ss != d) s += ews2[g][eidx(ss, d)];
        lws[g][d] = s * (1.f/7.f);
    }

    // --- S2': attention logits from x via w1s table ---
    {
        const int gg = lane >> 5, nn = (lane >> 2) & 7, hh = lane & 3;
        float s = 0.f, d = 0.f;
#pragma unroll
        for (int k = 0; k < 9; ++k) {
            const float xv = xw[gg][nn*9 + k];
            s = fmaf(xv, w1sL[k*8 + hh], s);
            d = fmaf(xv, w1sL[k*8 + 4 + hh], d);
        }
        als1[lane] = s; ald1[lane] = d;
    }
    __syncthreads();   // B2: lws, als1, ald1

    // --- S3: softmax layer1; lane -> (g, dst, h) -> alpha1b (bf16) ---
    {
        const int gg = lane >> 5, dd = (lane >> 2) & 7, hh = lane & 3;
        const float ce = cesL[hh], ad = ald1[gg*32 + dd*4 + hh];
        float lg[8], mx = -1e30f;
#pragma unroll
        for (int ss = 0; ss < 8; ++ss) {
            const float w = (ss == dd) ? lws[gg][dd] : ews2[gg][eidx(ss, dd)];
            float t = als1[gg*32 + ss*4 + hh] + ad + ce * w;
            t = lrelu(t);
            lg[ss] = t; mx = fmaxf(mx, t);
        }
        float sum = 0.f;
#pragma unroll
        for (int ss = 0; ss < 8; ++ss) { lg[ss] = __expf(lg[ss] - mx); sum += lg[ss]; }
        const float inv = 1.f / (sum + 1e-16f);
        ushort8 ap;
#pragma unroll
        for (int ss = 0; ss < 8; ++ss) ap[ss] = f2bf(lg[ss] * inv);
        *(ushort8*)&alpha1b[gg][hh][dd][0] = ap;
    }
    __syncthreads();   // B3: alpha1b

    // --- y = alpha @ x  (per-lane: its A-row's group/node, all 4 heads) ---
    float y[4][9];
    {
        float af[4][8];
#pragma unroll
        for (int h = 0; h < 4; ++h) {
            const ushort8 a8 = *(const ushort8*)&alpha1b[gA][h][nA][0];
#pragma unroll
            for (int s = 0; s < 8; ++s) af[h][s] = bf2f(a8[s]);
        }
#pragma unroll
        for (int k = 0; k < 9; ++k) {
            float xk[8];
#pragma unroll
            for (int s = 0; s < 8; ++s) xk[s] = xw[gA][s*9 + k];
#pragma unroll
            for (int h = 0; h < 4; ++h) {
                float a = 0.f;
#pragma unroll
                for (int s = 0; s < 8; ++s) a = fmaf(af[h][s], xk[s], a);
                y[h][k] = a;
            }
        }
    }

    // --- h1 fragment stream + GEMM2 MFMA: xp2[16][64] = h1[16][256] @ W2 ---
    // h1[rr][c], c = s*32 + o*8 + j  (head = s>>1), computed f32 then bf16.
    f32x4 acc[4] = {{0,0,0,0},{0,0,0,0},{0,0,0,0},{0,0,0,0}};
#pragma unroll
    for (int s = 0; s < 8; ++s) {
        const int h = s >> 1;
        const int cb = s*32 + o*8;
        float v[8];
        {
            const float4 bb0 = *(const float4*)(b1 + cb);
            const float4 bb1 = *(const float4*)(b1 + cb + 4);
            v[0]=bb0.x; v[1]=bb0.y; v[2]=bb0.z; v[3]=bb0.w;
            v[4]=bb1.x; v[5]=bb1.y; v[6]=bb1.z; v[7]=bb1.w;
        }
#pragma unroll
        for (int k = 0; k < 9; ++k) {
            const float4 w0 = *(const float4*)(W1 + k*256 + cb);
            const float4 w1 = *(const float4*)(W1 + k*256 + cb + 4);
            const float yv = y[h][k];
            v[0]=fmaf(yv,w0.x,v[0]); v[1]=fmaf(yv,w0.y,v[1]);
            v[2]=fmaf(yv,w0.z,v[2]); v[3]=fmaf(yv,w0.w,v[3]);
            v[4]=fmaf(yv,w1.x,v[4]); v[5]=fmaf(yv,w1.y,v[5]);
            v[6]=fmaf(yv,w1.z,v[6]); v[7]=fmaf(yv,w1.w,v[7]);
        }
        s16x8 A;
#pragma unroll
        for (int j = 0; j < 8; ++j) A[j] = (short)f2bf(eluf(v[j]));
#pragma unroll
        for (int t = 0; t < 4; ++t) {
            const s16x8 bf = *(const s16x8*)(wfrag + (size_t)(((t*8 + s)*64 + lane))*8);
            acc[t] = __builtin_amdgcn_mfma_f32_16x16x32_bf16(A, bf, acc[t], 0, 0, 0);
        }
    }

    // --- al_s2/al_d2 from C-layout (col = t*16 + (lane&15), row = 4*o + i) ---
    {
        const int c0 = lane & 15;
        float sp[4] = {0,0,0,0}, dp[4] = {0,0,0,0};
#pragma unroll
        for (int t = 0; t < 4; ++t) {
            const float as_ = a_src2[t*16 + c0];
            const float ad_ = a_dst2[t*16 + c0];
#pragma unroll
            for (int i = 0; i < 4; ++i) {
                sp[i] = fmaf(acc[t][i], as_, sp[i]);
                dp[i] = fmaf(acc[t][i], ad_, dp[i]);
            }
        }
#pragma unroll
        for (int i = 0; i < 4; ++i) {
            sp[i] += __shfl_xor(sp[i],1); sp[i] += __shfl_xor(sp[i],2);
            sp[i] += __shfl_xor(sp[i],4); sp[i] += __shfl_xor(sp[i],8);
            dp[i] += __shfl_xor(dp[i],1); dp[i] += __shfl_xor(dp[i],2);
            dp[i] += __shfl_xor(dp[i],4); dp[i] += __shfl_xor(dp[i],8);
        }
        if ((lane & 15) == 0) {
            const int rb = o * 4;
#pragma unroll
            for (int i = 0; i < 4; ++i) {
                const int r = rb + i;
                als2[r >> 3][r & 7] = sp[i];
                ald2[r >> 3][r & 7] = dp[i];
            }
        }
    }

    // --- store xp2 (f32) to xp2f, row stride 68 ---
    {
        const int c0 = lane & 15;
#pragma unroll
        for (int t = 0; t < 4; ++t)
#pragma unroll
            for (int i = 0; i < 4; ++i) {
                const int r = o*4 + i;
                xp2f[r >> 3][r & 7][t*16 + c0] = acc[t][i];
            }
    }
    __syncthreads();   // B4: xp2f, als2, ald2

    // --- softmax layer2; lanes<16 -> (g, dst) ---
    if (lane < 16) {
        const int g = lane >> 3, d = lane & 7;
        const float ce = cesL[4], ad = ald2[g][d];
        float lg[8], mx = -1e30f;
#pragma unroll
        for (int ss = 0; ss < 8; ++ss) {
            const float w = (ss == d) ? lws[g][d] : ews2[g][eidx(ss, d)];
            float t = als2[g][ss] + ad + ce * w;
            t = lrelu(t);
            lg[ss] = t; mx = fmaxf(mx, t);
        }
        float sum = 0.f;
#pragma unroll
        for (int ss = 0; ss < 8; ++ss) { lg[ss] = __expf(lg[ss] - mx); sum += lg[ss]; }
        const float inv = 1.f / (sum + 1e-16f);
#pragma unroll
        for (int ss = 0; ss < 8; ++ss) alpha2[g][d][ss] = lg[ss] * inv;
    }
    __syncthreads();   // B5: alpha2

    // --- aggregate2 + b2 + ELU + mean-pool -> embs16 (bf16) ---
    float h2[2][8];
#pragma unroll
    for (int g = 0; g < 2; ++g) {
        const float* xf = &xp2f[g][0][0];
        float a[8] = {0,0,0,0,0,0,0,0};
#pragma unroll
        for (int ss = 0; ss < 8; ++ss) {
            const float av = alpha2[g][n][ss];
            const float4 v0 = *(const float4*)(xf + ss*68 + cg*8);
            const float4 v1 = *(const float4*)(xf + ss*68 + cg*8 + 4);
            a[0]=fmaf(av,v0.x,a[0]); a[1]=fmaf(av,v0.y,a[1]);
            a[2]=fmaf(av,v0.z,a[2]); a[3]=fmaf(av,v0.w,a[3]);
            a[4]=fmaf(av,v1.x,a[4]); a[5]=fmaf(av,v1.y,a[5]);
            a[6]=fmaf(av,v1.z,a[6]); a[7]=fmaf(av,v1.w,a[7]);
        }
        const float4 b0 = *(const float4*)(b2 + cg*8);
        const float4 b1v = *(const float4*)(b2 + cg*8 + 4);
        h2[g][0]=eluf(a[0]+b0.x); h2[g][1]=eluf(a[1]+b0.y);
        h2[g][2]=eluf(a[2]+b0.z); h2[g][3]=eluf(a[3]+b0.w);
        h2[g][4]=eluf(a[4]+b1v.x); h2[g][5]=eluf(a[5]+b1v.y);
        h2[g][6]=eluf(a[6]+b1v.z); h2[g][7]=eluf(a[7]+b1v.w);
    }
#pragma unroll
    for (int g = 0; g < 2; ++g)
#pragma unroll
        for (int j = 0; j < 8; ++j) {
            float v = h2[g][j];
            v += __shfl_xor(v, 8); v += __shfl_xor(v, 16); v += __shfl_xor(v, 32);
            h2[g][j] = v * 0.125f;
        }
    if (n == 0) {       // lane < 8, cg = lane
#pragma unroll
        for (int g = 0; g < 2; ++g) {
            ushort8 p;
#pragma unroll
            for (int j = 0; j < 8; ++j) p[j] = f2bf(h2[g][j]);
            *(ushort8*)&embs16[g][lane*8] = p;
        }
    }
    __syncthreads();   // B6: embs16

    // --- readout via MFMA (M=2 rows used of 16) ---
    s16x8 aemb0 = {0,0,0,0,0,0,0,0}, aemb1 = {0,0,0,0,0,0,0,0};
    {
        const int r = lane & 15;
        if (r < 2) {
            aemb0 = *(const s16x8*)&embs16[r][o*8];
            aemb1 = *(const s16x8*)&embs16[r][32 + o*8];
        }
    }
    // r1 = relu(emb @ Wr1 + br1) -> r1s16 (bf16)
    {
        f32x4 ar[8];
        const f32x4 z = {0,0,0,0};
#pragma unroll
        for (int t = 0; t < 8; ++t) ar[t] = z;
#pragma unroll
        for (int t = 0; t < 8; ++t) {
            ar[t] = __builtin_amdgcn_mfma_f32_16x16x32_bf16(
                aemb0, *(const s16x8*)(wr1f + (size_t)((0*8 + t)*64 + lane)*8), ar[t], 0,0,0);
            ar[t] = __builtin_amdgcn_mfma_f32_16x16x32_bf16(
                aemb1, *(const s16x8*)(wr1f + (size_t)((1*8 + t)*64 + lane)*8), ar[t], 0,0,0);
        }
        const int c0 = lane & 15;
        if (o == 0) {
#pragma unroll
            for (int t = 0; t < 8; ++t) {
                const float bb = br1[t*16 + c0];
                r1s16[0][t*16 + c0] = f2bf(fmaxf(ar[t][0] + bb, 0.f));
                r1s16[1][t*16 + c0] = f2bf(fmaxf(ar[t][1] + bb, 0.f));
            }
        }
    }
    __syncthreads();   // B7: r1s16

    // recon = r1 @ Wr2 + br2  (direct global store)
    {
        f32x4 ac[5];
        const f32x4 z = {0,0,0,0};
#pragma unroll
        for (int t = 0; t < 5; ++t) ac[t] = z;
        const int r = lane & 15;
#pragma unroll
        for (int ks = 0; ks < 4; ++ks) {
            s16x8 a = {0,0,0,0,0,0,0,0};
            if (r < 2) a = *(const s16x8*)&r1s16[r][ks*32 + o*8];
#pragma unroll
            for (int t = 0; t < 5; ++t)
                ac[t] = __builtin_amdgcn_mfma_f32_16x16x32_bf16(
                    a, *(const s16x8*)(wr2f + (size_t)((ks*5 + t)*64 + lane)*8), ac[t], 0,0,0);
        }
        if (o == 0) {
            const int c0 = r;
#pragma unroll
            for (int t = 0; t < 5; ++t) {
                const int c = t*16 + c0;
                if (c < 72) {
                    const float bb = br2[c];
                    recon[(size_t)g0*72 + c]       = ac[t][0] + bb;
                    recon[(size_t)(g0+1)*72 + c]   = ac[t][1] + bb;
                }
            }
        }
    }

    // cls = relu(emb @ Wc1 + bc1) @ Wc2 + bc2
    {
        f32x4 ac[2];
        const f32x4 z = {0,0,0,0};
        ac[0] = z; ac[1] = z;
#pragma unroll
        for (int t = 0; t < 2; ++t) {
            ac[t] = __builtin_amdgcn_mfma_f32_16x16x32_bf16(
                aemb0, *(const s16x8*)(wc1f + (size_t)((0*2 + t)*64 + lane)*8), ac[t], 0,0,0);
            ac[t] = __builtin_amdgcn_mfma_f32_16x16x32_bf16(
                aemb1, *(const s16x8*)(wc1f + (size_t)((1*2 + t)*64 + lane)*8), ac[t], 0,0,0);
        }
        const int c0 = lane & 15;
        const float bb0 = bc1[c0], bb1 = bc1[16 + c0];
        const float wc0 = Wc2[c0], wc1v = Wc2[16 + c0];
        float p0 = fmaxf(ac[0][0] + bb0, 0.f)*wc0 + fmaxf(ac[1][0] + bb1, 0.f)*wc1v;
        float p1 = fmaxf(ac[0][1] + bb0, 0.f)*wc0 + fmaxf(ac[1][1] + bb1, 0.f)*wc1v;
        p0 += __shfl_xor(p0,1); p0 += __shfl_xor(p0,2); p0 += __shfl_xor(p0,4); p0 += __shfl_xor(p0,8);
        p1 += __shfl_xor(p1,1); p1 += __shfl_xor(p1,2); p1 += __shfl_xor(p1,4); p1 += __shfl_xor(p1,8);
        if (lane == 0) { cls[g0] = p0 + bc2[0]; cls[g0+1] = p1 + bc2[0]; }
    }
}

extern "C" void kernel_launch(void* const* d_in, const int* in_sizes, int n_in,
                              void* d_out, int out_size, void* d_ws, size_t ws_size,
                              hipStream_t stream) {
    const float* x      = (const float*)d_in[0];
    const float* ew     = (const float*)d_in[2];
    const float* W1     = (const float*)d_in[4];
    const float* a_src1 = (const float*)d_in[5];
    const float* a_dst1 = (const float*)d_in[6];
    const float* We1    = (const float*)d_in[7];
    const float* a_e1   = (const float*)d_in[8];
    const float* b1     = (const float*)d_in[9];
    const float* W2     = (const float*)d_in[10];
    const float* a_src2 = (const float*)d_in[11];
    const float* a_dst2 = (const float*)d_in[12];
    const float* We2    = (const float*)d_in[13];
    const float* a_e2   = (const float*)d_in[14];
    const float* b2     = (const float*)d_in[15];
    const float* Wr1    = (const float*)d_in[16];
    const float* br1    = (const float*)d_in[17];
    const float* Wr2    = (const float*)d_in[18];
    const float* br2    = (const float*)d_in[19];
    const float* Wc1    = (const float*)d_in[20];
    const float* bc1    = (const float*)d_in[21];
    const float* Wc2    = (const float*)d_in[22];
    const float* bc2    = (const float*)d_in[23];

    float* recon = (float*)d_out;
    float* cls   = (float*)d_out + (size_t)GROUPS * 72;

    char* ws = (char*)d_ws;
    u16*   wfrag = (u16*)(ws + 0);          // 32 KB
    u16*   wr1f  = (u16*)(ws + 32768);      // 16 KB
    u16*   wr2f  = (u16*)(ws + 49152);      // 20 KB
    u16*   wc1f  = (u16*)(ws + 69632);      // 4 KB
    float* w1s   = (float*)(ws + 73728);    // 288 B
    float* ces   = (float*)(ws + 74016);    // 24 B

    hipLaunchKernelGGL(prep, dim3(74), dim3(64), 0, stream,
                       W1, a_src1, a_dst1, W2, Wr1, Wr2, Wc1,
                       We1, a_e1, We2, a_e2,
                       wfrag, wr1f, wr2f, wc1f, w1s, ces);

    hipLaunchKernelGGL(gat_fused8, dim3(GROUPS/2), dim3(64), 0, stream,
                       x, ew, W1, b1, a_src2, a_dst2, b2,
                       br1, br2, bc1, Wc2, bc2,
                       wfrag, wr1f, wr2f, wc1f, w1s, ces,
                       recon, cls);
}

// Round 9
// 50.975 us; speedup vs baseline: 1.1827x; 1.0364x over previous
//
#include <hip/hip_runtime.h>
#include <math.h>

#define NEG 0.2f
#define GROUPS 8192

typedef unsigned short u16;
typedef u16 ushort8 __attribute__((ext_vector_type(8)));
typedef short s16x8 __attribute__((ext_vector_type(8)));
typedef float f32x4 __attribute__((ext_vector_type(4)));

__device__ __forceinline__ float lrelu(float x){ return x >= 0.f ? x : NEG*x; }
__device__ __forceinline__ float eluf(float x){ return x > 0.f ? x : __expf(x) - 1.f; }
__device__ __forceinline__ int eidx(int s,int d){ return s*7 + (d<s ? d : d-1); }
__device__ __forceinline__ float bf2f(u16 u){
    union { unsigned i; float f; } v; v.i = ((unsigned)u)<<16; return v.f;
}
__device__ __forceinline__ u16 f2bf(float f){
    union { float f; unsigned i; } v; v.f = f;
    unsigned r = v.i + 0x7fffu + ((v.i>>16)&1u);
    return (u16)(r>>16);
}

// ---------------------------------------------------------------------------
// prep: bf16 MFMA B-fragments for W2 (32), Wr1 (16), Wr2 (20, N 72->80),
// Wc1 (4); W1s table (attention vectors folded into x-space); ce scalars.
// Fragment f (1 KB): lane l holds B[k0 + (l>>4)*8 + j][c0 + (l&15)], j=0..7.
// ---------------------------------------------------------------------------
__global__ __launch_bounds__(64)
void prep(const float* __restrict__ W1, const float* __restrict__ a_src1,
          const float* __restrict__ a_dst1, const float* __restrict__ W2,
          const float* __restrict__ Wr1, const float* __restrict__ Wr2,
          const float* __restrict__ Wc1,
          const float* __restrict__ We1, const float* __restrict__ a_e1,
          const float* __restrict__ We2, const float* __restrict__ a_e2,
          u16* __restrict__ wfrag, u16* __restrict__ wr1f,
          u16* __restrict__ wr2f, u16* __restrict__ wc1f,
          float* __restrict__ w1s, float* __restrict__ ces)
{
    const int b = blockIdx.x, l = threadIdx.x;
    const int c0 = l & 15, o = l >> 4;
    if (b < 32) {                       // W2: 256x64, f = t*8+s
        const int t = b >> 3, s = b & 7;
        ushort8 p;
#pragma unroll
        for (int j = 0; j < 8; ++j) p[j] = f2bf(W2[(s*32 + o*8 + j)*64 + t*16 + c0]);
        *(ushort8*)(wfrag + (size_t)(b*64 + l)*8) = p;
    } else if (b < 48) {                // Wr1: 64x128, f = ks*8+t
        const int f = b - 32, ks = f >> 3, t = f & 7;
        ushort8 p;
#pragma unroll
        for (int j = 0; j < 8; ++j) p[j] = f2bf(Wr1[(ks*32 + o*8 + j)*128 + t*16 + c0]);
        *(ushort8*)(wr1f + (size_t)(f*64 + l)*8) = p;
    } else if (b < 68) {                // Wr2: 128x72 (pad N->80), f = ks*5+t
        const int f = b - 48, ks = f / 5, t = f % 5;
        const int c = t*16 + c0;
        ushort8 p;
#pragma unroll
        for (int j = 0; j < 8; ++j)
            p[j] = (c < 72) ? f2bf(Wr2[(ks*32 + o*8 + j)*72 + c]) : (u16)0;
        *(ushort8*)(wr2f + (size_t)(f*64 + l)*8) = p;
    } else if (b < 72) {                // Wc1: 64x32, f = ks*2+t
        const int f = b - 68, ks = f >> 1, t = f & 1;
        ushort8 p;
#pragma unroll
        for (int j = 0; j < 8; ++j) p[j] = f2bf(Wc1[(ks*32 + o*8 + j)*32 + t*16 + c0]);
        *(ushort8*)(wc1f + (size_t)(f*64 + l)*8) = p;
    } else if (b == 72) {               // W1s[k][cc]: cc<4 -> src h=cc, cc>=4 -> dst
        for (int idx = l; idx < 72; idx += 64) {
            const int k = idx >> 3, cc = idx & 7, h = cc & 3;
            const float* av = (cc < 4) ? a_src1 : a_dst1;
            float acc = 0.f;
#pragma unroll 8
            for (int i = 0; i < 64; ++i) acc = fmaf(W1[k*256 + h*64 + i], av[h*64 + i], acc);
            w1s[idx] = acc;
        }
    } else {                            // ce scalars
        if (l < 4) {
            float c = 0.f;
#pragma unroll 8
            for (int i = 0; i < 64; ++i) c = fmaf(We1[l*64+i], a_e1[l*64+i], c);
            ces[l] = c;
        } else if (l == 4) {
            float c = 0.f;
#pragma unroll 8
            for (int i = 0; i < 64; ++i) c = fmaf(We2[i], a_e2[i], c);
            ces[4] = c;
        }
    }
}

// ---------------------------------------------------------------------------
// One wave per block, 2 groups per wave. lane = n*8 + cg.
// out1 = (alpha @ x) @ W1: y = alpha@x computed COOPERATIVELY (lane (rr,o)
// does head o of row rr) into LDS yL[16][36]; h1 = ELU(y@W1+b1) streamed
// per k-octet directly into MFMA A-fragments. y kept in LDS (not registers)
// to fit the 64-arch-VGPR budget the allocator insists on (r5-r8 evidence:
// spills at ~90 live regs). Readout r1 split into two 4-acc halves.
// ---------------------------------------------------------------------------
__global__ __launch_bounds__(64, 4)
void gat_fused9(const float* __restrict__ x, const float* __restrict__ ew_g,
    const float* __restrict__ W1, const float* __restrict__ b1,
    const float* __restrict__ a_src2, const float* __restrict__ a_dst2,
    const float* __restrict__ b2,
    const float* __restrict__ br1, const float* __restrict__ br2,
    const float* __restrict__ bc1, const float* __restrict__ Wc2,
    const float* __restrict__ bc2,
    const u16* __restrict__ wfrag, const u16* __restrict__ wr1f,
    const u16* __restrict__ wr2f, const u16* __restrict__ wc1f,
    const float* __restrict__ w1s, const float* __restrict__ cesg,
    float* __restrict__ recon, float* __restrict__ cls)
{
    __shared__ __align__(16) float xw[2][72];
    __shared__ float ews2[2][56];
    __shared__ float lws[2][8];
    __shared__ float w1sL[72];
    __shared__ float cesL[6];
    __shared__ __align__(16) u16 alpha1b[2][4][8][8];   // bf16 [g][h][dst][src]
    __shared__ float als1[64], ald1[64];                // idx = g*32 + n*4 + h
    __shared__ float yL[16][36];                        // y = alpha@x, [row][h*9+k]
    __shared__ float als2[2][8], ald2[2][8];
    __shared__ float alpha2[2][8][8];
    __shared__ __align__(16) float xp2f[2][8][68];      // xp2, stride 68
    __shared__ __align__(16) u16 embs16[2][64];
    __shared__ __align__(16) u16 r1s16[2][128];

    const int lane = threadIdx.x;       // 0..63
    const int n    = lane >> 3;
    const int cg   = lane & 7;
    const int g0   = blockIdx.x * 2;
    const int o    = lane >> 4;         // k-octet (MFMA A)
    const int rr   = lane & 15;         // A row
    const int gA   = rr >> 3, nA = rr & 7;

    // --- stage x (2x72), edge weights (2x56), w1s, ces ---
    {
        const float* xg = x + (size_t)g0 * 72;
        for (int i = lane; i < 144; i += 64) (&xw[0][0])[i] = xg[i];
        const float* eg = ew_g + (size_t)g0 * 56;
        for (int i = lane; i < 112; i += 64) (&ews2[0][0])[i] = eg[i];
        for (int i = lane; i < 72; i += 64) w1sL[i] = w1s[i];
        if (lane < 6) cesL[lane] = cesg[lane];
    }
    __syncthreads();   // B1

    // self-loop attr = mean of 7 incoming edge weights
    if (lane < 16) {
        const int g = lane >> 3, d = lane & 7;
        float s = 0.f;
#pragma unroll
        for (int ss = 0; ss < 8; ++ss) if (ss != d) s += ews2[g][eidx(ss, d)];
        lws[g][d] = s * (1.f/7.f);
    }

    // --- S2': attention logits from x via w1s table ---
    {
        const int gg = lane >> 5, nn = (lane >> 2) & 7, hh = lane & 3;
        float s = 0.f, d = 0.f;
#pragma unroll
        for (int k = 0; k < 9; ++k) {
            const float xv = xw[gg][nn*9 + k];
            s = fmaf(xv, w1sL[k*8 + hh], s);
            d = fmaf(xv, w1sL[k*8 + 4 + hh], d);
        }
        als1[lane] = s; ald1[lane] = d;
    }
    __syncthreads();   // B2: lws, als1, ald1

    // --- S3: softmax layer1; lane -> (g, dst, h) -> alpha1b (bf16) ---
    {
        const int gg = lane >> 5, dd = (lane >> 2) & 7, hh = lane & 3;
        const float ce = cesL[hh], ad = ald1[gg*32 + dd*4 + hh];
        float lg[8], mx = -1e30f;
#pragma unroll
        for (int ss = 0; ss < 8; ++ss) {
            const float w = (ss == dd) ? lws[gg][dd] : ews2[gg][eidx(ss, dd)];
            float t = als1[gg*32 + ss*4 + hh] + ad + ce * w;
            t = lrelu(t);
            lg[ss] = t; mx = fmaxf(mx, t);
        }
        float sum = 0.f;
#pragma unroll
        for (int ss = 0; ss < 8; ++ss) { lg[ss] = __expf(lg[ss] - mx); sum += lg[ss]; }
        const float inv = 1.f / (sum + 1e-16f);
        ushort8 ap;
#pragma unroll
        for (int ss = 0; ss < 8; ++ss) ap[ss] = f2bf(lg[ss] * inv);
        *(ushort8*)&alpha1b[gg][hh][dd][0] = ap;
    }
    __syncthreads();   // B3: alpha1b

    // --- y = alpha @ x, cooperative: lane (rr, o) computes head o of row rr ---
    {
        const ushort8 a8 = *(const ushort8*)&alpha1b[gA][o][nA][0];
        float af[8];
#pragma unroll
        for (int s = 0; s < 8; ++s) af[s] = bf2f(a8[s]);
#pragma unroll
        for (int k = 0; k < 9; ++k) {
            float a = 0.f;
#pragma unroll
            for (int s = 0; s < 8; ++s) a = fmaf(af[s], xw[gA][s*9 + k], a);
            yL[rr][o*9 + k] = a;
        }
    }
    __syncthreads();   // B4: yL

    // --- h1 fragment stream + GEMM2 MFMA: xp2[16][64] = h1[16][256] @ W2 ---
    // h1[rr][c], c = s*32 + o*8 + j  (head = s>>1), f32 -> bf16 A-frag.
    f32x4 acc[4] = {{0,0,0,0},{0,0,0,0},{0,0,0,0},{0,0,0,0}};
#pragma unroll
    for (int s = 0; s < 8; ++s) {
        const int h = s >> 1;
        const int cb = s*32 + o*8;
        float v[8];
        {
            const float4 bb0 = *(const float4*)(b1 + cb);
            const float4 bb1 = *(const float4*)(b1 + cb + 4);
            v[0]=bb0.x; v[1]=bb0.y; v[2]=bb0.z; v[3]=bb0.w;
            v[4]=bb1.x; v[5]=bb1.y; v[6]=bb1.z; v[7]=bb1.w;
        }
#pragma unroll
        for (int k = 0; k < 9; ++k) {
            const float yv = yL[rr][h*9 + k];
            const float4 w0 = *(const float4*)(W1 + k*256 + cb);
            const float4 w1 = *(const float4*)(W1 + k*256 + cb + 4);
            v[0]=fmaf(yv,w0.x,v[0]); v[1]=fmaf(yv,w0.y,v[1]);
            v[2]=fmaf(yv,w0.z,v[2]); v[3]=fmaf(yv,w0.w,v[3]);
            v[4]=fmaf(yv,w1.x,v[4]); v[5]=fmaf(yv,w1.y,v[5]);
            v[6]=fmaf(yv,w1.z,v[6]); v[7]=fmaf(yv,w1.w,v[7]);
        }
        s16x8 A;
#pragma unroll
        for (int j = 0; j < 8; ++j) A[j] = (short)f2bf(eluf(v[j]));
#pragma unroll
        for (int t = 0; t < 4; ++t) {
            const s16x8 bf = *(const s16x8*)(wfrag + (size_t)(((t*8 + s)*64 + lane))*8);
            acc[t] = __builtin_amdgcn_mfma_f32_16x16x32_bf16(A, bf, acc[t], 0, 0, 0);
        }
    }

    // --- al_s2/al_d2 from C-layout (col = t*16 + (lane&15), row = 4*o + i) ---
    {
        const int c0 = lane & 15;
        float sp[4] = {0,0,0,0}, dp[4] = {0,0,0,0};
#pragma unroll
        for (int t = 0; t < 4; ++t) {
            const float as_ = a_src2[t*16 + c0];
            const float ad_ = a_dst2[t*16 + c0];
#pragma unroll
            for (int i = 0; i < 4; ++i) {
                sp[i] = fmaf(acc[t][i], as_, sp[i]);
                dp[i] = fmaf(acc[t][i], ad_, dp[i]);
            }
        }
#pragma unroll
        for (int i = 0; i < 4; ++i) {
            sp[i] += __shfl_xor(sp[i],1); sp[i] += __shfl_xor(sp[i],2);
            sp[i] += __shfl_xor(sp[i],4); sp[i] += __shfl_xor(sp[i],8);
            dp[i] += __shfl_xor(dp[i],1); dp[i] += __shfl_xor(dp[i],2);
            dp[i] += __shfl_xor(dp[i],4); dp[i] += __shfl_xor(dp[i],8);
        }
        if ((lane & 15) == 0) {
            const int rb = o * 4;
#pragma unroll
            for (int i = 0; i < 4; ++i) {
                const int r = rb + i;
                als2[r >> 3][r & 7] = sp[i];
                ald2[r >> 3][r & 7] = dp[i];
            }
        }
    }

    // --- store xp2 (f32) to xp2f, row stride 68 ---
    {
        const int c0 = lane & 15;
#pragma unroll
        for (int t = 0; t < 4; ++t)
#pragma unroll
            for (int i = 0; i < 4; ++i) {
                const int r = o*4 + i;
                xp2f[r >> 3][r & 7][t*16 + c0] = acc[t][i];
            }
    }
    __syncthreads();   // B5: xp2f, als2, ald2

    // --- softmax layer2; lanes<16 -> (g, dst) ---
    if (lane < 16) {
        const int g = lane >> 3, d = lane & 7;
        const float ce = cesL[4], ad = ald2[g][d];
        float lg[8], mx = -1e30f;
#pragma unroll
        for (int ss = 0; ss < 8; ++ss) {
            const float w = (ss == d) ? lws[g][d] : ews2[g][eidx(ss, d)];
            float t = als2[g][ss] + ad + ce * w;
            t = lrelu(t);
            lg[ss] = t; mx = fmaxf(mx, t);
        }
        float sum = 0.f;
#pragma unroll
        for (int ss = 0; ss < 8; ++ss) { lg[ss] = __expf(lg[ss] - mx); sum += lg[ss]; }
        const float inv = 1.f / (sum + 1e-16f);
#pragma unroll
        for (int ss = 0; ss < 8; ++ss) alpha2[g][d][ss] = lg[ss] * inv;
    }
    __syncthreads();   // B6: alpha2

    // --- aggregate2 + b2 + ELU + mean-pool -> embs16 (bf16) ---
    float h2[2][8];
#pragma unroll
    for (int g = 0; g < 2; ++g) {
        const float* xf = &xp2f[g][0][0];
        float a[8] = {0,0,0,0,0,0,0,0};
#pragma unroll
        for (int ss = 0; ss < 8; ++ss) {
            const float av = alpha2[g][n][ss];
            const float4 v0 = *(const float4*)(xf + ss*68 + cg*8);
            const float4 v1 = *(const float4*)(xf + ss*68 + cg*8 + 4);
            a[0]=fmaf(av,v0.x,a[0]); a[1]=fmaf(av,v0.y,a[1]);
            a[2]=fmaf(av,v0.z,a[2]); a[3]=fmaf(av,v0.w,a[3]);
            a[4]=fmaf(av,v1.x,a[4]); a[5]=fmaf(av,v1.y,a[5]);
            a[6]=fmaf(av,v1.z,a[6]); a[7]=fmaf(av,v1.w,a[7]);
        }
        const float4 b0 = *(const float4*)(b2 + cg*8);
        const float4 b1v = *(const float4*)(b2 + cg*8 + 4);
        h2[g][0]=eluf(a[0]+b0.x); h2[g][1]=eluf(a[1]+b0.y);
        h2[g][2]=eluf(a[2]+b0.z); h2[g][3]=eluf(a[3]+b0.w);
        h2[g][4]=eluf(a[4]+b1v.x); h2[g][5]=eluf(a[5]+b1v.y);
        h2[g][6]=eluf(a[6]+b1v.z); h2[g][7]=eluf(a[7]+b1v.w);
    }
#pragma unroll
    for (int g = 0; g < 2; ++g)
#pragma unroll
        for (int j = 0; j < 8; ++j) {
            float v = h2[g][j];
            v += __shfl_xor(v, 8); v += __shfl_xor(v, 16); v += __shfl_xor(v, 32);
            h2[g][j] = v * 0.125f;
        }
    if (n == 0) {       // lane < 8, cg = lane
#pragma unroll
        for (int g = 0; g < 2; ++g) {
            ushort8 p;
#pragma unroll
            for (int j = 0; j < 8; ++j) p[j] = f2bf(h2[g][j]);
            *(ushort8*)&embs16[g][lane*8] = p;
        }
    }
    __syncthreads();   // B7: embs16

    // --- readout via MFMA (M=2 rows used of 16) ---
    s16x8 aemb0 = {0,0,0,0,0,0,0,0}, aemb1 = {0,0,0,0,0,0,0,0};
    {
        const int r = lane & 15;
        if (r < 2) {
            aemb0 = *(const s16x8*)&embs16[r][o*8];
            aemb1 = *(const s16x8*)&embs16[r][32 + o*8];
        }
    }
    // r1 = relu(emb @ Wr1 + br1) -> r1s16 (bf16); two 4-acc halves
#pragma unroll
    for (int half = 0; half < 2; ++half) {
        f32x4 ar[4];
        const f32x4 z = {0,0,0,0};
#pragma unroll
        for (int t = 0; t < 4; ++t) ar[t] = z;
#pragma unroll
        for (int t = 0; t < 4; ++t) {
            const int tt = half*4 + t;
            ar[t] = __builtin_amdgcn_mfma_f32_16x16x32_bf16(
                aemb0, *(const s16x8*)(wr1f + (size_t)((0*8 + tt)*64 + lane)*8), ar[t], 0,0,0);
            ar[t] = __builtin_amdgcn_mfma_f32_16x16x32_bf16(
                aemb1, *(const s16x8*)(wr1f + (size_t)((1*8 + tt)*64 + lane)*8), ar[t], 0,0,0);
        }
        const int c0 = lane & 15;
        if (o == 0) {
#pragma unroll
            for (int t = 0; t < 4; ++t) {
                const int tt = half*4 + t;
                const float bb = br1[tt*16 + c0];
                r1s16[0][tt*16 + c0] = f2bf(fmaxf(ar[t][0] + bb, 0.f));
                r1s16[1][tt*16 + c0] = f2bf(fmaxf(ar[t][1] + bb, 0.f));
            }
        }
    }
    __syncthreads();   // B8: r1s16

    // recon = r1 @ Wr2 + br2  (direct global store)
    {
        f32x4 ac[5];
        const f32x4 z = {0,0,0,0};
#pragma unroll
        for (int t = 0; t < 5; ++t) ac[t] = z;
        const int r = lane & 15;
#pragma unroll
        for (int ks = 0; ks < 4; ++ks) {
            s16x8 a = {0,0,0,0,0,0,0,0};
            if (r < 2) a = *(const s16x8*)&r1s16[r][ks*32 + o*8];
#pragma unroll
            for (int t = 0; t < 5; ++t)
                ac[t] = __builtin_amdgcn_mfma_f32_16x16x32_bf16(
                    a, *(const s16x8*)(wr2f + (size_t)((ks*5 + t)*64 + lane)*8), ac[t], 0,0,0);
        }
        if (o == 0) {
            const int c0 = r;
#pragma unroll
            for (int t = 0; t < 5; ++t) {
                const int c = t*16 + c0;
                if (c < 72) {
                    const float bb = br2[c];
                    recon[(size_t)g0*72 + c]       = ac[t][0] + bb;
                    recon[(size_t)(g0+1)*72 + c]   = ac[t][1] + bb;
                }
            }
        }
    }

    // cls = relu(emb @ Wc1 + bc1) @ Wc2 + bc2
    {
        f32x4 ac[2];
        const f32x4 z = {0,0,0,0};
        ac[0] = z; ac[1] = z;
#pragma unroll
        for (int t = 0; t < 2; ++t) {
            ac[t] = __builtin_amdgcn_mfma_f32_16x16x32_bf16(
                aemb0, *(const s16x8*)(wc1f + (size_t)((0*2 + t)*64 + lane)*8), ac[t], 0,0,0);
            ac[t] = __builtin_amdgcn_mfma_f32_16x16x32_bf16(
                aemb1, *(const s16x8*)(wc1f + (size_t)((1*2 + t)*64 + lane)*8), ac[t], 0,0,0);
        }
        const int c0 = lane & 15;
        const float bb0 = bc1[c0], bb1 = bc1[16 + c0];
        const float wc0 = Wc2[c0], wc1v = Wc2[16 + c0];
        float p0 = fmaxf(ac[0][0] + bb0, 0.f)*wc0 + fmaxf(ac[1][0] + bb1, 0.f)*wc1v;
        float p1 = fmaxf(ac[0][1] + bb0, 0.f)*wc0 + fmaxf(ac[1][1] + bb1, 0.f)*wc1v;
        p0 += __shfl_xor(p0,1); p0 += __shfl_xor(p0,2); p0 += __shfl_xor(p0,4); p0 += __shfl_xor(p0,8);
        p1 += __shfl_xor(p1,1); p1 += __shfl_xor(p1,2); p1 += __shfl_xor(p1,4); p1 += __shfl_xor(p1,8);
        if (lane == 0) { cls[g0] = p0 + bc2[0]; cls[g0+1] = p1 + bc2[0]; }
    }
}

extern "C" void kernel_launch(void* const* d_in, const int* in_sizes, int n_in,
                              void* d_out, int out_size, void* d_ws, size_t ws_size,
                              hipStream_t stream) {
    const float* x      = (const float*)d_in[0];
    const float* ew     = (const float*)d_in[2];
    const float* W1     = (const float*)d_in[4];
    const float* a_src1 = (const float*)d_in[5];
    const float* a_dst1 = (const float*)d_in[6];
    const float* We1    = (const float*)d_in[7];
    const float* a_e1   = (const float*)d_in[8];
    const float* b1     = (const float*)d_in[9];
    const float* W2     = (const float*)d_in[10];
    const float* a_src2 = (const float*)d_in[11];
    const float* a_dst2 = (const float*)d_in[12];
    const float* We2    = (const float*)d_in[13];
    const float* a_e2   = (const float*)d_in[14];
    const float* b2     = (const float*)d_in[15];
    const float* Wr1    = (const float*)d_in[16];
    const float* br1    = (const float*)d_in[17];
    const float* Wr2    = (const float*)d_in[18];
    const float* br2    = (const float*)d_in[19];
    const float* Wc1    = (const float*)d_in[20];
    const float* bc1    = (const float*)d_in[21];
    const float* Wc2    = (const float*)d_in[22];
    const float* bc2    = (const float*)d_in[23];

    float* recon = (float*)d_out;
    float* cls   = (float*)d_out + (size_t)GROUPS * 72;

    char* ws = (char*)d_ws;
    u16*   wfrag = (u16*)(ws + 0);          // 32 KB
    u16*   wr1f  = (u16*)(ws + 32768);      // 16 KB
    u16*   wr2f  = (u16*)(ws + 49152);      // 20 KB
    u16*   wc1f  = (u16*)(ws + 69632);      // 4 KB
    float* w1s   = (float*)(ws + 73728);    // 288 B
    float* ces   = (float*)(ws + 74016);    // 24 B

    hipLaunchKernelGGL(prep, dim3(74), dim3(64), 0, stream,
                       W1, a_src1, a_dst1, W2, Wr1, Wr2, Wc1,
                       We1, a_e1, We2, a_e2,
                       wfrag, wr1f, wr2f, wc1f, w1s, ces);

    hipLaunchKernelGGL(gat_fused9, dim3(GROUPS/2), dim3(64), 0, stream,
                       x, ew, W1, b1, a_src2, a_dst2, b2,
                       br1, br2, bc1, Wc2, bc2,
                       wfrag, wr1f, wr2f, wc1f, w1s, ces,
                       recon, cls);
}

// Round 10
// 44.180 us; speedup vs baseline: 1.3646x; 1.1538x over previous
//
#include <hip/hip_runtime.h>
#include <math.h>

#define NEG 0.2f
#define GROUPS 8192

typedef unsigned short u16;
typedef u16 ushort8 __attribute__((ext_vector_type(8)));
typedef short s16x8 __attribute__((ext_vector_type(8)));
typedef float f32x4 __attribute__((ext_vector_type(4)));

__device__ __forceinline__ float lrelu(float x){ return x >= 0.f ? x : NEG*x; }
__device__ __forceinline__ float eluf(float x){ return x > 0.f ? x : __expf(x) - 1.f; }
__device__ __forceinline__ int eidx(int s,int d){ return s*7 + (d<s ? d : d-1); }
__device__ __forceinline__ float bf2f(u16 u){
    union { unsigned i; float f; } v; v.i = ((unsigned)u)<<16; return v.f;
}
__device__ __forceinline__ u16 f2bf(float f){
    union { float f; unsigned i; } v; v.f = f;
    unsigned r = v.i + 0x7fffu + ((v.i>>16)&1u);
    return (u16)(r>>16);
}

// ---------------------------------------------------------------------------
// prep: bf16 MFMA B-fragments for W2 (32, K-PERMUTED: k = o*64 + s*8 + j so
// the A-side k-octet o == head index), Wr1 (16), Wr2 (20, N 72->80), Wc1 (4);
// W1s table; ce scalars.
// Fragment f (1 KB): lane l holds B[k(l,f)][c0 + (l&15)], j=0..7.
// ---------------------------------------------------------------------------
__global__ __launch_bounds__(64)
void prep(const float* __restrict__ W1, const float* __restrict__ a_src1,
          const float* __restrict__ a_dst1, const float* __restrict__ W2,
          const float* __restrict__ Wr1, const float* __restrict__ Wr2,
          const float* __restrict__ Wc1,
          const float* __restrict__ We1, const float* __restrict__ a_e1,
          const float* __restrict__ We2, const float* __restrict__ a_e2,
          u16* __restrict__ wfrag, u16* __restrict__ wr1f,
          u16* __restrict__ wr2f, u16* __restrict__ wc1f,
          float* __restrict__ w1s, float* __restrict__ ces)
{
    const int b = blockIdx.x, l = threadIdx.x;
    const int c0 = l & 15, o = l >> 4;
    if (b < 32) {                       // W2: 256x64, f = t*8+s, K-permuted
        const int t = b >> 3, s = b & 7;
        ushort8 p;
#pragma unroll
        for (int j = 0; j < 8; ++j) p[j] = f2bf(W2[(o*64 + s*8 + j)*64 + t*16 + c0]);
        *(ushort8*)(wfrag + (size_t)(b*64 + l)*8) = p;
    } else if (b < 48) {                // Wr1: 64x128, f = ks*8+t
        const int f = b - 32, ks = f >> 3, t = f & 7;
        ushort8 p;
#pragma unroll
        for (int j = 0; j < 8; ++j) p[j] = f2bf(Wr1[(ks*32 + o*8 + j)*128 + t*16 + c0]);
        *(ushort8*)(wr1f + (size_t)(f*64 + l)*8) = p;
    } else if (b < 68) {                // Wr2: 128x72 (pad N->80), f = ks*5+t
        const int f = b - 48, ks = f / 5, t = f % 5;
        const int c = t*16 + c0;
        ushort8 p;
#pragma unroll
        for (int j = 0; j < 8; ++j)
            p[j] = (c < 72) ? f2bf(Wr2[(ks*32 + o*8 + j)*72 + c]) : (u16)0;
        *(ushort8*)(wr2f + (size_t)(f*64 + l)*8) = p;
    } else if (b < 72) {                // Wc1: 64x32, f = ks*2+t
        const int f = b - 68, ks = f >> 1, t = f & 1;
        ushort8 p;
#pragma unroll
        for (int j = 0; j < 8; ++j) p[j] = f2bf(Wc1[(ks*32 + o*8 + j)*32 + t*16 + c0]);
        *(ushort8*)(wc1f + (size_t)(f*64 + l)*8) = p;
    } else if (b == 72) {               // W1s[k][cc]: cc<4 -> src h=cc, cc>=4 -> dst
        for (int idx = l; idx < 72; idx += 64) {
            const int k = idx >> 3, cc = idx & 7, h = cc & 3;
            const float* av = (cc < 4) ? a_src1 : a_dst1;
            float acc = 0.f;
#pragma unroll 8
            for (int i = 0; i < 64; ++i) acc = fmaf(W1[k*256 + h*64 + i], av[h*64 + i], acc);
            w1s[idx] = acc;
        }
    } else {                            // ce scalars
        if (l < 4) {
            float c = 0.f;
#pragma unroll 8
            for (int i = 0; i < 64; ++i) c = fmaf(We1[l*64+i], a_e1[l*64+i], c);
            ces[l] = c;
        } else if (l == 4) {
            float c = 0.f;
#pragma unroll 8
            for (int i = 0; i < 64; ++i) c = fmaf(We2[i], a_e2[i], c);
            ces[4] = c;
        }
    }
}

// ---------------------------------------------------------------------------
// One wave per block, 2 groups per wave. lane = n*8 + cg.
// out1 = (alpha @ x) @ W1. GEMM2's K-dim is PERMUTED (c = o*64 + s*8 + j,
// matching wfrag) so a lane's k-octet o IS the head index: y = alpha_o @ x
// (9 floats) stays entirely in registers — no yL LDS array, no extra barrier.
// LDS ~8.7 KB -> 18 blocks/CU: whole 4096-block grid co-resident (needs 16).
// 64-arch-VGPR discipline (r9 lesson): keep live set small, real __shared__
// arrays only, no overlays.
// ---------------------------------------------------------------------------
__global__ __launch_bounds__(64, 4)
void gat_fused10(const float* __restrict__ x, const float* __restrict__ ew_g,
    const float* __restrict__ W1, const float* __restrict__ b1,
    const float* __restrict__ a_src2, const float* __restrict__ a_dst2,
    const float* __restrict__ b2,
    const float* __restrict__ br1, const float* __restrict__ br2,
    const float* __restrict__ bc1, const float* __restrict__ Wc2,
    const float* __restrict__ bc2,
    const u16* __restrict__ wfrag, const u16* __restrict__ wr1f,
    const u16* __restrict__ wr2f, const u16* __restrict__ wc1f,
    const float* __restrict__ w1s, const float* __restrict__ cesg,
    float* __restrict__ recon, float* __restrict__ cls)
{
    __shared__ __align__(16) float xw[2][72];
    __shared__ float ews2[2][56];
    __shared__ float lws[2][8];
    __shared__ float w1sL[72];
    __shared__ float cesL[6];
    __shared__ __align__(16) u16 alpha1b[2][4][8][8];   // bf16 [g][h][dst][src]
    __shared__ float als1[64], ald1[64];                // idx = g*32 + n*4 + h
    __shared__ float als2[2][8], ald2[2][8];
    __shared__ float alpha2[2][8][8];
    __shared__ __align__(16) float xp2f[2][8][68];      // xp2, stride 68
    __shared__ __align__(16) u16 embs16[2][64];
    __shared__ __align__(16) u16 r1s16[2][128];

    const int lane = threadIdx.x;       // 0..63
    const int n    = lane >> 3;
    const int cg   = lane & 7;
    const int g0   = blockIdx.x * 2;
    const int o    = lane >> 4;         // k-octet == head (permuted K)
    const int rr   = lane & 15;         // A row
    const int gA   = rr >> 3, nA = rr & 7;

    // --- stage x (2x72), edge weights (2x56), w1s, ces ---
    {
        const float* xg = x + (size_t)g0 * 72;
        for (int i = lane; i < 144; i += 64) (&xw[0][0])[i] = xg[i];
        const float* eg = ew_g + (size_t)g0 * 56;
        for (int i = lane; i < 112; i += 64) (&ews2[0][0])[i] = eg[i];
        for (int i = lane; i < 72; i += 64) w1sL[i] = w1s[i];
        if (lane < 6) cesL[lane] = cesg[lane];
    }
    __syncthreads();   // B1

    // self-loop attr = mean of 7 incoming edge weights
    if (lane < 16) {
        const int g = lane >> 3, d = lane & 7;
        float s = 0.f;
#pragma unroll
        for (int ss = 0; ss < 8; ++ss) if (ss != d) s += ews2[g][eidx(ss, d)];
        lws[g][d] = s * (1.f/7.f);
    }

    // --- S2': attention logits from x via w1s table ---
    {
        const int gg = lane >> 5, nn = (lane >> 2) & 7, hh = lane & 3;
        float s = 0.f, d = 0.f;
#pragma unroll
        for (int k = 0; k < 9; ++k) {
            const float xv = xw[gg][nn*9 + k];
            s = fmaf(xv, w1sL[k*8 + hh], s);
            d = fmaf(xv, w1sL[k*8 + 4 + hh], d);
        }
        als1[lane] = s; ald1[lane] = d;
    }
    __syncthreads();   // B2: lws, als1, ald1

    // --- S3: softmax layer1; lane -> (g, dst, h) -> alpha1b (bf16) ---
    {
        const int gg = lane >> 5, dd = (lane >> 2) & 7, hh = lane & 3;
        const float ce = cesL[hh], ad = ald1[gg*32 + dd*4 + hh];
        float lg[8], mx = -1e30f;
#pragma unroll
        for (int ss = 0; ss < 8; ++ss) {
            const float w = (ss == dd) ? lws[gg][dd] : ews2[gg][eidx(ss, dd)];
            float t = als1[gg*32 + ss*4 + hh] + ad + ce * w;
            t = lrelu(t);
            lg[ss] = t; mx = fmaxf(mx, t);
        }
        float sum = 0.f;
#pragma unroll
        for (int ss = 0; ss < 8; ++ss) { lg[ss] = __expf(lg[ss] - mx); sum += lg[ss]; }
        const float inv = 1.f / (sum + 1e-16f);
        ushort8 ap;
#pragma unroll
        for (int ss = 0; ss < 8; ++ss) ap[ss] = f2bf(lg[ss] * inv);
        *(ushort8*)&alpha1b[gg][hh][dd][0] = ap;
    }
    __syncthreads();   // B3: alpha1b

    // --- y = alpha_o @ x for this lane's (row rr, head o): 9 registers ---
    float y[9];
    {
        const ushort8 a8 = *(const ushort8*)&alpha1b[gA][o][nA][0];
        float af[8];
#pragma unroll
        for (int s = 0; s < 8; ++s) af[s] = bf2f(a8[s]);
#pragma unroll
        for (int k = 0; k < 9; ++k) {
            float a = 0.f;
#pragma unroll
            for (int s = 0; s < 8; ++s) a = fmaf(af[s], xw[gA][s*9 + k], a);
            y[k] = a;
        }
    }

    // --- h1 fragment stream + GEMM2 MFMA (K-permuted): c = o*64 + s*8 + j ---
    f32x4 acc[4] = {{0,0,0,0},{0,0,0,0},{0,0,0,0},{0,0,0,0}};
#pragma unroll
    for (int s = 0; s < 8; ++s) {
        const int cb = o*64 + s*8;
        float v[8];
        {
            const float4 bb0 = *(const float4*)(b1 + cb);
            const float4 bb1 = *(const float4*)(b1 + cb + 4);
            v[0]=bb0.x; v[1]=bb0.y; v[2]=bb0.z; v[3]=bb0.w;
            v[4]=bb1.x; v[5]=bb1.y; v[6]=bb1.z; v[7]=bb1.w;
        }
#pragma unroll
        for (int k = 0; k < 9; ++k) {
            const float yv = y[k];
            const float4 w0 = *(const float4*)(W1 + k*256 + cb);
            const float4 w1 = *(const float4*)(W1 + k*256 + cb + 4);
            v[0]=fmaf(yv,w0.x,v[0]); v[1]=fmaf(yv,w0.y,v[1]);
            v[2]=fmaf(yv,w0.z,v[2]); v[3]=fmaf(yv,w0.w,v[3]);
            v[4]=fmaf(yv,w1.x,v[4]); v[5]=fmaf(yv,w1.y,v[5]);
            v[6]=fmaf(yv,w1.z,v[6]); v[7]=fmaf(yv,w1.w,v[7]);
        }
        s16x8 A;
#pragma unroll
        for (int j = 0; j < 8; ++j) A[j] = (short)f2bf(eluf(v[j]));
#pragma unroll
        for (int t = 0; t < 4; ++t) {
            const s16x8 bf = *(const s16x8*)(wfrag + (size_t)(((t*8 + s)*64 + lane))*8);
            acc[t] = __builtin_amdgcn_mfma_f32_16x16x32_bf16(A, bf, acc[t], 0, 0, 0);
        }
    }

    // --- al_s2/al_d2 from C-layout (col = t*16 + (lane&15), row = 4*o + i) ---
    {
        const int c0 = lane & 15;
        float sp[4] = {0,0,0,0}, dp[4] = {0,0,0,0};
#pragma unroll
        for (int t = 0; t < 4; ++t) {
            const float as_ = a_src2[t*16 + c0];
            const float ad_ = a_dst2[t*16 + c0];
#pragma unroll
            for (int i = 0; i < 4; ++i) {
                sp[i] = fmaf(acc[t][i], as_, sp[i]);
                dp[i] = fmaf(acc[t][i], ad_, dp[i]);
            }
        }
#pragma unroll
        for (int i = 0; i < 4; ++i) {
            sp[i] += __shfl_xor(sp[i],1); sp[i] += __shfl_xor(sp[i],2);
            sp[i] += __shfl_xor(sp[i],4); sp[i] += __shfl_xor(sp[i],8);
            dp[i] += __shfl_xor(dp[i],1); dp[i] += __shfl_xor(dp[i],2);
            dp[i] += __shfl_xor(dp[i],4); dp[i] += __shfl_xor(dp[i],8);
        }
        if ((lane & 15) == 0) {
            const int rb = o * 4;
#pragma unroll
            for (int i = 0; i < 4; ++i) {
                const int r = rb + i;
                als2[r >> 3][r & 7] = sp[i];
                ald2[r >> 3][r & 7] = dp[i];
            }
        }
    }

    // --- store xp2 (f32) to xp2f, row stride 68 ---
    {
        const int c0 = lane & 15;
#pragma unroll
        for (int t = 0; t < 4; ++t)
#pragma unroll
            for (int i = 0; i < 4; ++i) {
                const int r = o*4 + i;
                xp2f[r >> 3][r & 7][t*16 + c0] = acc[t][i];
            }
    }
    __syncthreads();   // B4: xp2f, als2, ald2

    // --- softmax layer2; lanes<16 -> (g, dst) ---
    if (lane < 16) {
        const int g = lane >> 3, d = lane & 7;
        const float ce = cesL[4], ad = ald2[g][d];
        float lg[8], mx = -1e30f;
#pragma unroll
        for (int ss = 0; ss < 8; ++ss) {
            const float w = (ss == d) ? lws[g][d] : ews2[g][eidx(ss, d)];
            float t = als2[g][ss] + ad + ce * w;
            t = lrelu(t);
            lg[ss] = t; mx = fmaxf(mx, t);
        }
        float sum = 0.f;
#pragma unroll
        for (int ss = 0; ss < 8; ++ss) { lg[ss] = __expf(lg[ss] - mx); sum += lg[ss]; }
        const float inv = 1.f / (sum + 1e-16f);
#pragma unroll
        for (int ss = 0; ss < 8; ++ss) alpha2[g][d][ss] = lg[ss] * inv;
    }
    __syncthreads();   // B5: alpha2

    // --- aggregate2 + b2 + ELU + mean-pool -> embs16 (bf16) ---
    float h2[2][8];
#pragma unroll
    for (int g = 0; g < 2; ++g) {
        const float* xf = &xp2f[g][0][0];
        float a[8] = {0,0,0,0,0,0,0,0};
#pragma unroll
        for (int ss = 0; ss < 8; ++ss) {
            const float av = alpha2[g][n][ss];
            const float4 v0 = *(const float4*)(xf + ss*68 + cg*8);
            const float4 v1 = *(const float4*)(xf + ss*68 + cg*8 + 4);
            a[0]=fmaf(av,v0.x,a[0]); a[1]=fmaf(av,v0.y,a[1]);
            a[2]=fmaf(av,v0.z,a[2]); a[3]=fmaf(av,v0.w,a[3]);
            a[4]=fmaf(av,v1.x,a[4]); a[5]=fmaf(av,v1.y,a[5]);
            a[6]=fmaf(av,v1.z,a[6]); a[7]=fmaf(av,v1.w,a[7]);
        }
        const float4 b0 = *(const float4*)(b2 + cg*8);
        const float4 b1v = *(const float4*)(b2 + cg*8 + 4);
        h2[g][0]=eluf(a[0]+b0.x); h2[g][1]=eluf(a[1]+b0.y);
        h2[g][2]=eluf(a[2]+b0.z); h2[g][3]=eluf(a[3]+b0.w);
        h2[g][4]=eluf(a[4]+b1v.x); h2[g][5]=eluf(a[5]+b1v.y);
        h2[g][6]=eluf(a[6]+b1v.z); h2[g][7]=eluf(a[7]+b1v.w);
    }
#pragma unroll
    for (int g = 0; g < 2; ++g)
#pragma unroll
        for (int j = 0; j < 8; ++j) {
            float v = h2[g][j];
            v += __shfl_xor(v, 8); v += __shfl_xor(v, 16); v += __shfl_xor(v, 32);
            h2[g][j] = v * 0.125f;
        }
    if (n == 0) {       // lane < 8, cg = lane
#pragma unroll
        for (int g = 0; g < 2; ++g) {
            ushort8 p;
#pragma unroll
            for (int j = 0; j < 8; ++j) p[j] = f2bf(h2[g][j]);
            *(ushort8*)&embs16[g][lane*8] = p;
        }
    }
    __syncthreads();   // B6: embs16

    // --- readout via MFMA (M=2 rows used of 16) ---
    s16x8 aemb0 = {0,0,0,0,0,0,0,0}, aemb1 = {0,0,0,0,0,0,0,0};
    {
        const int r = lane & 15;
        if (r < 2) {
            aemb0 = *(const s16x8*)&embs16[r][o*8];
            aemb1 = *(const s16x8*)&embs16[r][32 + o*8];
        }
    }
    // r1 = relu(emb @ Wr1 + br1) -> r1s16 (bf16); two 4-acc halves
#pragma unroll
    for (int half = 0; half < 2; ++half) {
        f32x4 ar[4];
        const f32x4 z = {0,0,0,0};
#pragma unroll
        for (int t = 0; t < 4; ++t) ar[t] = z;
#pragma unroll
        for (int t = 0; t < 4; ++t) {
            const int tt = half*4 + t;
            ar[t] = __builtin_amdgcn_mfma_f32_16x16x32_bf16(
                aemb0, *(const s16x8*)(wr1f + (size_t)((0*8 + tt)*64 + lane)*8), ar[t], 0,0,0);
            ar[t] = __builtin_amdgcn_mfma_f32_16x16x32_bf16(
                aemb1, *(const s16x8*)(wr1f + (size_t)((1*8 + tt)*64 + lane)*8), ar[t], 0,0,0);
        }
        const int c0 = lane & 15;
        if (o == 0) {
#pragma unroll
            for (int t = 0; t < 4; ++t) {
                const int tt = half*4 + t;
                const float bb = br1[tt*16 + c0];
                r1s16[0][tt*16 + c0] = f2bf(fmaxf(ar[t][0] + bb, 0.f));
                r1s16[1][tt*16 + c0] = f2bf(fmaxf(ar[t][1] + bb, 0.f));
            }
        }
    }
    __syncthreads();   // B7: r1s16

    // recon = r1 @ Wr2 + br2  (direct global store)
    {
        f32x4 ac[5];
        const f32x4 z = {0,0,0,0};
#pragma unroll
        for (int t = 0; t < 5; ++t) ac[t] = z;
        const int r = lane & 15;
#pragma unroll
        for (int ks = 0; ks < 4; ++ks) {
            s16x8 a = {0,0,0,0,0,0,0,0};
            if (r < 2) a = *(const s16x8*)&r1s16[r][ks*32 + o*8];
#pragma unroll
            for (int t = 0; t < 5; ++t)
                ac[t] = __builtin_amdgcn_mfma_f32_16x16x32_bf16(
                    a, *(const s16x8*)(wr2f + (size_t)((ks*5 + t)*64 + lane)*8), ac[t], 0,0,0);
        }
        if (o == 0) {
            const int c0 = r;
#pragma unroll
            for (int t = 0; t < 5; ++t) {
                const int c = t*16 + c0;
                if (c < 72) {
                    const float bb = br2[c];
                    recon[(size_t)g0*72 + c]       = ac[t][0] + bb;
                    recon[(size_t)(g0+1)*72 + c]   = ac[t][1] + bb;
                }
            }
        }
    }

    // cls = relu(emb @ Wc1 + bc1) @ Wc2 + bc2
    {
        f32x4 ac[2];
        const f32x4 z = {0,0,0,0};
        ac[0] = z; ac[1] = z;
#pragma unroll
        for (int t = 0; t < 2; ++t) {
            ac[t] = __builtin_amdgcn_mfma_f32_16x16x32_bf16(
                aemb0, *(const s16x8*)(wc1f + (size_t)((0*2 + t)*64 + lane)*8), ac[t], 0,0,0);
            ac[t] = __builtin_amdgcn_mfma_f32_16x16x32_bf16(
                aemb1, *(const s16x8*)(wc1f + (size_t)((1*2 + t)*64 + lane)*8), ac[t], 0,0,0);
        }
        const int c0 = lane & 15;
        const float bb0 = bc1[c0], bb1 = bc1[16 + c0];
        const float wc0 = Wc2[c0], wc1v = Wc2[16 + c0];
        float p0 = fmaxf(ac[0][0] + bb0, 0.f)*wc0 + fmaxf(ac[1][0] + bb1, 0.f)*wc1v;
        float p1 = fmaxf(ac[0][1] + bb0, 0.f)*wc0 + fmaxf(ac[1][1] + bb1, 0.f)*wc1v;
        p0 += __shfl_xor(p0,1); p0 += __shfl_xor(p0,2); p0 += __shfl_xor(p0,4); p0 += __shfl_xor(p0,8);
        p1 += __shfl_xor(p1,1); p1 += __shfl_xor(p1,2); p1 += __shfl_xor(p1,4); p1 += __shfl_xor(p1,8);
        if (lane == 0) { cls[g0] = p0 + bc2[0]; cls[g0+1] = p1 + bc2[0]; }
    }
}

extern "C" void kernel_launch(void* const* d_in, const int* in_sizes, int n_in,
                              void* d_out, int out_size, void* d_ws, size_t ws_size,
                              hipStream_t stream) {
    const float* x      = (const float*)d_in[0];
    const float* ew     = (const float*)d_in[2];
    const float* W1     = (const float*)d_in[4];
    const float* a_src1 = (const float*)d_in[5];
    const float* a_dst1 = (const float*)d_in[6];
    const float* We1    = (const float*)d_in[7];
    const float* a_e1   = (const float*)d_in[8];
    const float* b1     = (const float*)d_in[9];
    const float* W2     = (const float*)d_in[10];
    const float* a_src2 = (const float*)d_in[11];
    const float* a_dst2 = (const float*)d_in[12];
    const float* We2    = (const float*)d_in[13];
    const float* a_e2   = (const float*)d_in[14];
    const float* b2     = (const float*)d_in[15];
    const float* Wr1    = (const float*)d_in[16];
    const float* br1    = (const float*)d_in[17];
    const float* Wr2    = (const float*)d_in[18];
    const float* br2    = (const float*)d_in[19];
    const float* Wc1    = (const float*)d_in[20];
    const float* bc1    = (const float*)d_in[21];
    const float* Wc2    = (const float*)d_in[22];
    const float* bc2    = (const float*)d_in[23];

    float* recon = (float*)d_out;
    float* cls   = (float*)d_out + (size_t)GROUPS * 72;

    char* ws = (char*)d_ws;
    u16*   wfrag = (u16*)(ws + 0);          // 32 KB
    u16*   wr1f  = (u16*)(ws + 32768);      // 16 KB
    u16*   wr2f  = (u16*)(ws + 49152);      // 20 KB
    u16*   wc1f  = (u16*)(ws + 69632);      // 4 KB
    float* w1s   = (float*)(ws + 73728);    // 288 B
    float* ces   = (float*)(ws + 74016);    // 24 B

    hipLaunchKernelGGL(prep, dim3(74), dim3(64), 0, stream,
                       W1, a_src1, a_dst1, W2, Wr1, Wr2, Wc1,
                       We1, a_e1, We2, a_e2,
                       wfrag, wr1f, wr2f, wc1f, w1s, ces);

    hipLaunchKernelGGL(gat_fused10, dim3(GROUPS/2), dim3(64), 0, stream,
                       x, ew, W1, b1, a_src2, a_dst2, b2,
                       br1, br2, bc1, Wc2, bc2,
                       wfrag, wr1f, wr2f, wc1f, w1s, ces,
                       recon, cls);
}

// Round 11
// 44.018 us; speedup vs baseline: 1.3696x; 1.0037x over previous
//
#include <hip/hip_runtime.h>
#include <math.h>

#define NEG 0.2f
#define GROUPS 8192

typedef unsigned short u16;
typedef u16 ushort8 __attribute__((ext_vector_type(8)));
typedef short s16x8 __attribute__((ext_vector_type(8)));
typedef float f32x4 __attribute__((ext_vector_type(4)));

__device__ __forceinline__ float lrelu(float x){ return x >= 0.f ? x : NEG*x; }
__device__ __forceinline__ float eluf(float x){ return x > 0.f ? x : __expf(x) - 1.f; }
__device__ __forceinline__ int eidx(int s,int d){ return s*7 + (d<s ? d : d-1); }
__device__ __forceinline__ float bf2f(u16 u){
    union { unsigned i; float f; } v; v.i = ((unsigned)u)<<16; return v.f;
}
__device__ __forceinline__ u16 f2bf(float f){
    union { float f; unsigned i; } v; v.f = f;
    unsigned r = v.i + 0x7fffu + ((v.i>>16)&1u);
    return (u16)(r>>16);
}

// ---------------------------------------------------------------------------
// prep: bf16 MFMA B-fragments for W2 (32, K-PERMUTED: k = o*64 + s*8 + j so
// the A-side k-octet o == head index), Wr1 (16), Wr2 (20, N 72->80), Wc1 (4);
// W1s table; ce scalars.  Fragment f (1 KB): lane l holds B[k][c0+(l&15)].
// ---------------------------------------------------------------------------
__global__ __launch_bounds__(64)
void prep(const float* __restrict__ W1, const float* __restrict__ a_src1,
          const float* __restrict__ a_dst1, const float* __restrict__ W2,
          const float* __restrict__ Wr1, const float* __restrict__ Wr2,
          const float* __restrict__ Wc1,
          const float* __restrict__ We1, const float* __restrict__ a_e1,
          const float* __restrict__ We2, const float* __restrict__ a_e2,
          u16* __restrict__ wfrag, u16* __restrict__ wr1f,
          u16* __restrict__ wr2f, u16* __restrict__ wc1f,
          float* __restrict__ w1s, float* __restrict__ ces)
{
    const int b = blockIdx.x, l = threadIdx.x;
    const int c0 = l & 15, o = l >> 4;
    if (b < 32) {                       // W2: 256x64, f = t*8+s, K-permuted
        const int t = b >> 3, s = b & 7;
        ushort8 p;
#pragma unroll
        for (int j = 0; j < 8; ++j) p[j] = f2bf(W2[(o*64 + s*8 + j)*64 + t*16 + c0]);
        *(ushort8*)(wfrag + (size_t)(b*64 + l)*8) = p;
    } else if (b < 48) {                // Wr1: 64x128, f = ks*8+t
        const int f = b - 32, ks = f >> 3, t = f & 7;
        ushort8 p;
#pragma unroll
        for (int j = 0; j < 8; ++j) p[j] = f2bf(Wr1[(ks*32 + o*8 + j)*128 + t*16 + c0]);
        *(ushort8*)(wr1f + (size_t)(f*64 + l)*8) = p;
    } else if (b < 68) {                // Wr2: 128x72 (pad N->80), f = ks*5+t
        const int f = b - 48, ks = f / 5, t = f % 5;
        const int c = t*16 + c0;
        ushort8 p;
#pragma unroll
        for (int j = 0; j < 8; ++j)
            p[j] = (c < 72) ? f2bf(Wr2[(ks*32 + o*8 + j)*72 + c]) : (u16)0;
        *(ushort8*)(wr2f + (size_t)(f*64 + l)*8) = p;
    } else if (b < 72) {                // Wc1: 64x32, f = ks*2+t
        const int f = b - 68, ks = f >> 1, t = f & 1;
        ushort8 p;
#pragma unroll
        for (int j = 0; j < 8; ++j) p[j] = f2bf(Wc1[(ks*32 + o*8 + j)*32 + t*16 + c0]);
        *(ushort8*)(wc1f + (size_t)(f*64 + l)*8) = p;
    } else if (b == 72) {               // W1s[k][cc]: cc<4 -> src h=cc, cc>=4 -> dst
        for (int idx = l; idx < 72; idx += 64) {
            const int k = idx >> 3, cc = idx & 7, h = cc & 3;
            const float* av = (cc < 4) ? a_src1 : a_dst1;
            float acc = 0.f;
#pragma unroll 8
            for (int i = 0; i < 64; ++i) acc = fmaf(W1[k*256 + h*64 + i], av[h*64 + i], acc);
            w1s[idx] = acc;
        }
    } else {                            // ce scalars
        if (l < 4) {
            float c = 0.f;
#pragma unroll 8
            for (int i = 0; i < 64; ++i) c = fmaf(We1[l*64+i], a_e1[l*64+i], c);
            ces[l] = c;
        } else if (l == 4) {
            float c = 0.f;
#pragma unroll 8
            for (int i = 0; i < 64; ++i) c = fmaf(We2[i], a_e2[i], c);
            ces[4] = c;
        }
    }
}

// ---------------------------------------------------------------------------
// One wave per block, 2 groups per wave. lane = n*8 + cg.
// Register/shfl dataflow: alpha1 and alpha2 are NEVER stored to LDS —
// S3's normalized alphas travel to the y-stage by __shfl (producer lane
// gA*32+nA*4+o holds exactly the 8 alphas lane (rr,o) needs); softmax2 runs
// on all lanes from butterfly registers and aggregate2 shfls from lane g*8+n.
// Barriers: 4 (staging, xp2f, embs16, r1s16). LDS ~6.5 KB.
// ---------------------------------------------------------------------------
__global__ __launch_bounds__(64, 4)
void gat_fused11(const float* __restrict__ x, const float* __restrict__ ew_g,
    const float* __restrict__ W1, const float* __restrict__ b1,
    const float* __restrict__ a_src2, const float* __restrict__ a_dst2,
    const float* __restrict__ b2,
    const float* __restrict__ br1, const float* __restrict__ br2,
    const float* __restrict__ bc1, const float* __restrict__ Wc2,
    const float* __restrict__ bc2,
    const u16* __restrict__ wfrag, const u16* __restrict__ wr1f,
    const u16* __restrict__ wr2f, const u16* __restrict__ wc1f,
    const float* __restrict__ w1s, const float* __restrict__ cesg,
    float* __restrict__ recon, float* __restrict__ cls)
{
    __shared__ __align__(16) float xw[2][72];
    __shared__ float ews2[2][56];
    __shared__ float w1sL[72];
    __shared__ float cesL[6];
    __shared__ __align__(16) float xp2f[2][8][68];      // xp2, stride 68
    __shared__ __align__(16) u16 embs16[2][64];
    __shared__ __align__(16) u16 r1s16[2][128];

    const int lane = threadIdx.x;       // 0..63
    const int n    = lane >> 3;
    const int cg   = lane & 7;
    const int g0   = blockIdx.x * 2;
    const int o    = lane >> 4;         // k-octet == head (permuted K)
    const int rr   = lane & 15;         // A row
    const int gA   = rr >> 3, nA = rr & 7;

    // --- stage x (2x72), edge weights (2x56), w1s, ces ---
    {
        const float* xg = x + (size_t)g0 * 72;
        for (int i = lane; i < 144; i += 64) (&xw[0][0])[i] = xg[i];
        const float* eg = ew_g + (size_t)g0 * 56;
        for (int i = lane; i < 112; i += 64) (&ews2[0][0])[i] = eg[i];
        for (int i = lane; i < 72; i += 64) w1sL[i] = w1s[i];
        if (lane < 6) cesL[lane] = cesg[lane];
    }
    __syncthreads();   // B1: all staging

    // --- S2': attention logits from x via w1s; lane (gg,nn,hh), regs only ---
    float alsv = 0.f, aldv = 0.f;
    {
        const int gg = lane >> 5, nn = (lane >> 2) & 7, hh = lane & 3;
        float s = 0.f, d = 0.f;
#pragma unroll
        for (int k = 0; k < 9; ++k) {
            const float xv = xw[gg][nn*9 + k];
            s = fmaf(xv, w1sL[k*8 + hh], s);
            d = fmaf(xv, w1sL[k*8 + 4 + hh], d);
        }
        alsv = s; aldv = d;
    }

    // --- S3: softmax layer1; lane -> (gg, dd, hh); als via shfl; lws per-lane;
    //     output: normalized alphas lgn[8] IN REGISTERS ---
    float lgn[8];
    {
        const int gg = lane >> 5, dd = (lane >> 2) & 7, hh = lane & 3;
        float lw = 0.f;
#pragma unroll
        for (int ss = 0; ss < 8; ++ss) if (ss != dd) lw += ews2[gg][eidx(ss, dd)];
        lw *= (1.f/7.f);
        const float ce = cesL[hh];
        float mx = -1e30f;
#pragma unroll
        for (int ss = 0; ss < 8; ++ss) {
            const float as_ = __shfl(alsv, (lane & 0x23) | (ss << 2));
            const float w = (ss == dd) ? lw : ews2[gg][eidx(ss, dd)];
            float t = as_ + aldv + ce * w;
            t = lrelu(t);
            lgn[ss] = t; mx = fmaxf(mx, t);
        }
        float sum = 0.f;
#pragma unroll
        for (int ss = 0; ss < 8; ++ss) { lgn[ss] = __expf(lgn[ss] - mx); sum += lgn[ss]; }
        const float inv = 1.f / (sum + 1e-16f);
#pragma unroll
        for (int ss = 0; ss < 8; ++ss) lgn[ss] *= inv;
    }

    // --- y = alpha_o @ x for lane (row rr, head o): alphas via shfl ---
    float y[9];
    {
        const int src = gA*32 + nA*4 + o;   // S3 producer lane for (gA, nA, o)
#pragma unroll
        for (int k = 0; k < 9; ++k) y[k] = 0.f;
#pragma unroll
        for (int ss = 0; ss < 8; ++ss) {
            const float av = __shfl(lgn[ss], src);
#pragma unroll
            for (int k = 0; k < 9; ++k) y[k] = fmaf(av, xw[gA][ss*9 + k], y[k]);
        }
    }

    // --- h1 fragment stream + GEMM2 MFMA (K-permuted): c = o*64 + s*8 + j ---
    f32x4 acc[4] = {{0,0,0,0},{0,0,0,0},{0,0,0,0},{0,0,0,0}};
#pragma unroll
    for (int s = 0; s < 8; ++s) {
        const int cb = o*64 + s*8;
        float v[8];
        {
            const float4 bb0 = *(const float4*)(b1 + cb);
            const float4 bb1 = *(const float4*)(b1 + cb + 4);
            v[0]=bb0.x; v[1]=bb0.y; v[2]=bb0.z; v[3]=bb0.w;
            v[4]=bb1.x; v[5]=bb1.y; v[6]=bb1.z; v[7]=bb1.w;
        }
#pragma unroll
        for (int k = 0; k < 9; ++k) {
            const float yv = y[k];
            const float4 w0 = *(const float4*)(W1 + k*256 + cb);
            const float4 w1 = *(const float4*)(W1 + k*256 + cb + 4);
            v[0]=fmaf(yv,w0.x,v[0]); v[1]=fmaf(yv,w0.y,v[1]);
            v[2]=fmaf(yv,w0.z,v[2]); v[3]=fmaf(yv,w0.w,v[3]);
            v[4]=fmaf(yv,w1.x,v[4]); v[5]=fmaf(yv,w1.y,v[5]);
            v[6]=fmaf(yv,w1.z,v[6]); v[7]=fmaf(yv,w1.w,v[7]);
        }
        s16x8 A;
#pragma unroll
        for (int j = 0; j < 8; ++j) A[j] = (short)f2bf(eluf(v[j]));
#pragma unroll
        for (int t = 0; t < 4; ++t) {
            const s16x8 bf = *(const s16x8*)(wfrag + (size_t)(((t*8 + s)*64 + lane))*8);
            acc[t] = __builtin_amdgcn_mfma_f32_16x16x32_bf16(A, bf, acc[t], 0, 0, 0);
        }
    }

    // --- al_s2/al_d2 dots + 16-lane butterfly (rows 4*o+i in registers) ---
    float sp[4] = {0,0,0,0}, dp[4] = {0,0,0,0};
    {
        const int c0 = lane & 15;
#pragma unroll
        for (int t = 0; t < 4; ++t) {
            const float as_ = a_src2[t*16 + c0];
            const float ad_ = a_dst2[t*16 + c0];
#pragma unroll
            for (int i = 0; i < 4; ++i) {
                sp[i] = fmaf(acc[t][i], as_, sp[i]);
                dp[i] = fmaf(acc[t][i], ad_, dp[i]);
            }
        }
#pragma unroll
        for (int i = 0; i < 4; ++i) {
            sp[i] += __shfl_xor(sp[i],1); sp[i] += __shfl_xor(sp[i],2);
            sp[i] += __shfl_xor(sp[i],4); sp[i] += __shfl_xor(sp[i],8);
            dp[i] += __shfl_xor(dp[i],1); dp[i] += __shfl_xor(dp[i],2);
            dp[i] += __shfl_xor(dp[i],4); dp[i] += __shfl_xor(dp[i],8);
        }
    }

    // --- softmax layer2 on ALL lanes (g=(lane>>3)&1, d=lane&7), regs only ---
    float lg2n[8];
    {
        const int g = (lane >> 3) & 1, d = lane & 7;
        float al[8];
#pragma unroll
        for (int ss = 0; ss < 8; ++ss)
            al[ss] = __shfl(sp[ss & 3], (g*2 + (ss >> 2)) * 16);
        const int srcd = (g*2 + (d >> 2)) * 16;
        const float q0 = __shfl(dp[0], srcd), q1 = __shfl(dp[1], srcd);
        const float q2 = __shfl(dp[2], srcd), q3 = __shfl(dp[3], srcd);
        const float ad = (d & 2) ? ((d & 1) ? q3 : q2) : ((d & 1) ? q1 : q0);
        float lw = 0.f;
#pragma unroll
        for (int ss = 0; ss < 8; ++ss) if (ss != d) lw += ews2[g][eidx(ss, d)];
        lw *= (1.f/7.f);
        const float ce = cesL[4];
        float mx = -1e30f;
#pragma unroll
        for (int ss = 0; ss < 8; ++ss) {
            const float w = (ss == d) ? lw : ews2[g][eidx(ss, d)];
            float t = al[ss] + ad + ce * w;
            t = lrelu(t);
            lg2n[ss] = t; mx = fmaxf(mx, t);
        }
        float sum = 0.f;
#pragma unroll
        for (int ss = 0; ss < 8; ++ss) { lg2n[ss] = __expf(lg2n[ss] - mx); sum += lg2n[ss]; }
        const float inv = 1.f / (sum + 1e-16f);
#pragma unroll
        for (int ss = 0; ss < 8; ++ss) lg2n[ss] *= inv;
    }

    // --- store xp2 (f32) to xp2f, row stride 68 ---
    {
        const int c0 = lane & 15;
#pragma unroll
        for (int t = 0; t < 4; ++t)
#pragma unroll
            for (int i = 0; i < 4; ++i) {
                const int r = o*4 + i;
                xp2f[r >> 3][r & 7][t*16 + c0] = acc[t][i];
            }
    }
    __syncthreads();   // B2: xp2f

    // --- aggregate2 + b2 + ELU + mean-pool -> embs16 (alpha2 via shfl) ---
    float h2[2][8];
#pragma unroll
    for (int g = 0; g < 2; ++g) {
        const float* xf = &xp2f[g][0][0];
        const int srcg = g*8 + n;   // softmax2 producer lane for (g, d=n)
        float a[8] = {0,0,0,0,0,0,0,0};
#pragma unroll
        for (int ss = 0; ss < 8; ++ss) {
            const float av = __shfl(lg2n[ss], srcg);
            const float4 v0 = *(const float4*)(xf + ss*68 + cg*8);
            const float4 v1 = *(const float4*)(xf + ss*68 + cg*8 + 4);
            a[0]=fmaf(av,v0.x,a[0]); a[1]=fmaf(av,v0.y,a[1]);
            a[2]=fmaf(av,v0.z,a[2]); a[3]=fmaf(av,v0.w,a[3]);
            a[4]=fmaf(av,v1.x,a[4]); a[5]=fmaf(av,v1.y,a[5]);
            a[6]=fmaf(av,v1.z,a[6]); a[7]=fmaf(av,v1.w,a[7]);
        }
        const float4 b0 = *(const float4*)(b2 + cg*8);
        const float4 b1v = *(const float4*)(b2 + cg*8 + 4);
        h2[g][0]=eluf(a[0]+b0.x); h2[g][1]=eluf(a[1]+b0.y);
        h2[g][2]=eluf(a[2]+b0.z); h2[g][3]=eluf(a[3]+b0.w);
        h2[g][4]=eluf(a[4]+b1v.x); h2[g][5]=eluf(a[5]+b1v.y);
        h2[g][6]=eluf(a[6]+b1v.z); h2[g][7]=eluf(a[7]+b1v.w);
    }
#pragma unroll
    for (int g = 0; g < 2; ++g)
#pragma unroll
        for (int j = 0; j < 8; ++j) {
            float v = h2[g][j];
            v += __shfl_xor(v, 8); v += __shfl_xor(v, 16); v += __shfl_xor(v, 32);
            h2[g][j] = v * 0.125f;
        }
    if (n == 0) {       // lane < 8, cg = lane
#pragma unroll
        for (int g = 0; g < 2; ++g) {
            ushort8 p;
#pragma unroll
            for (int j = 0; j < 8; ++j) p[j] = f2bf(h2[g][j]);
            *(ushort8*)&embs16[g][lane*8] = p;
        }
    }
    __syncthreads();   // B3: embs16

    // --- readout via MFMA (M=2 rows used of 16) ---
    s16x8 aemb0 = {0,0,0,0,0,0,0,0}, aemb1 = {0,0,0,0,0,0,0,0};
    {
        const int r = lane & 15;
        if (r < 2) {
            aemb0 = *(const s16x8*)&embs16[r][o*8];
            aemb1 = *(const s16x8*)&embs16[r][32 + o*8];
        }
    }
    // r1 = relu(emb @ Wr1 + br1) -> r1s16 (bf16); two 4-acc halves
#pragma unroll
    for (int half = 0; half < 2; ++half) {
        f32x4 ar[4];
        const f32x4 z = {0,0,0,0};
#pragma unroll
        for (int t = 0; t < 4; ++t) ar[t] = z;
#pragma unroll
        for (int t = 0; t < 4; ++t) {
            const int tt = half*4 + t;
            ar[t] = __builtin_amdgcn_mfma_f32_16x16x32_bf16(
                aemb0, *(const s16x8*)(wr1f + (size_t)((0*8 + tt)*64 + lane)*8), ar[t], 0,0,0);
            ar[t] = __builtin_amdgcn_mfma_f32_16x16x32_bf16(
                aemb1, *(const s16x8*)(wr1f + (size_t)((1*8 + tt)*64 + lane)*8), ar[t], 0,0,0);
        }
        const int c0 = lane & 15;
        if (o == 0) {
#pragma unroll
            for (int t = 0; t < 4; ++t) {
                const int tt = half*4 + t;
                const float bb = br1[tt*16 + c0];
                r1s16[0][tt*16 + c0] = f2bf(fmaxf(ar[t][0] + bb, 0.f));
                r1s16[1][tt*16 + c0] = f2bf(fmaxf(ar[t][1] + bb, 0.f));
            }
        }
    }
    __syncthreads();   // B4: r1s16

    // recon = r1 @ Wr2 + br2  (direct global store)
    {
        f32x4 ac[5];
        const f32x4 z = {0,0,0,0};
#pragma unroll
        for (int t = 0; t < 5; ++t) ac[t] = z;
        const int r = lane & 15;
#pragma unroll
        for (int ks = 0; ks < 4; ++ks) {
            s16x8 a = {0,0,0,0,0,0,0,0};
            if (r < 2) a = *(const s16x8*)&r1s16[r][ks*32 + o*8];
#pragma unroll
            for (int t = 0; t < 5; ++t)
                ac[t] = __builtin_amdgcn_mfma_f32_16x16x32_bf16(
                    a, *(const s16x8*)(wr2f + (size_t)((ks*5 + t)*64 + lane)*8), ac[t], 0,0,0);
        }
        if (o == 0) {
            const int c0 = r;
#pragma unroll
            for (int t = 0; t < 5; ++t) {
                const int c = t*16 + c0;
                if (c < 72) {
                    const float bb = br2[c];
                    recon[(size_t)g0*72 + c]       = ac[t][0] + bb;
                    recon[(size_t)(g0+1)*72 + c]   = ac[t][1] + bb;
                }
            }
        }
    }

    // cls = relu(emb @ Wc1 + bc1) @ Wc2 + bc2
    {
        f32x4 ac[2];
        const f32x4 z = {0,0,0,0};
        ac[0] = z; ac[1] = z;
#pragma unroll
        for (int t = 0; t < 2; ++t) {
            ac[t] = __builtin_amdgcn_mfma_f32_16x16x32_bf16(
                aemb0, *(const s16x8*)(wc1f + (size_t)((0*2 + t)*64 + lane)*8), ac[t], 0,0,0);
            ac[t] = __builtin_amdgcn_mfma_f32_16x16x32_bf16(
                aemb1, *(const s16x8*)(wc1f + (size_t)((1*2 + t)*64 + lane)*8), ac[t], 0,0,0);
        }
        const int c0 = lane & 15;
        const float bb0 = bc1[c0], bb1 = bc1[16 + c0];
        const float wc0 = Wc2[c0], wc1v = Wc2[16 + c0];
        float p0 = fmaxf(ac[0][0] + bb0, 0.f)*wc0 + fmaxf(ac[1][0] + bb1, 0.f)*wc1v;
        float p1 = fmaxf(ac[0][1] + bb0, 0.f)*wc0 + fmaxf(ac[1][1] + bb1, 0.f)*wc1v;
        p0 += __shfl_xor(p0,1); p0 += __shfl_xor(p0,2); p0 += __shfl_xor(p0,4); p0 += __shfl_xor(p0,8);
        p1 += __shfl_xor(p1,1); p1 += __shfl_xor(p1,2); p1 += __shfl_xor(p1,4); p1 += __shfl_xor(p1,8);
        if (lane == 0) { cls[g0] = p0 + bc2[0]; cls[g0+1] = p1 + bc2[0]; }
    }
}

extern "C" void kernel_launch(void* const* d_in, const int* in_sizes, int n_in,
                              void* d_out, int out_size, void* d_ws, size_t ws_size,
                              hipStream_t stream) {
    const float* x      = (const float*)d_in[0];
    const float* ew     = (const float*)d_in[2];
    const float* W1     = (const float*)d_in[4];
    const float* a_src1 = (const float*)d_in[5];
    const float* a_dst1 = (const float*)d_in[6];
    const float* We1    = (const float*)d_in[7];
    const float* a_e1   = (const float*)d_in[8];
    const float* b1     = (const float*)d_in[9];
    const float* W2     = (const float*)d_in[10];
    const float* a_src2 = (const float*)d_in[11];
    const float* a_dst2 = (const float*)d_in[12];
    const float* We2    = (const float*)d_in[13];
    const float* a_e2   = (const float*)d_in[14];
    const float* b2     = (const float*)d_in[15];
    const float* Wr1    = (const float*)d_in[16];
    const float* br1    = (const float*)d_in[17];
    const float* Wr2    = (const float*)d_in[18];
    const float* br2    = (const float*)d_in[19];
    const float* Wc1    = (const float*)d_in[20];
    const float* bc1    = (const float*)d_in[21];
    const float* Wc2    = (const float*)d_in[22];
    const float* bc2    = (const float*)d_in[23];

    float* recon = (float*)d_out;
    float* cls   = (float*)d_out + (size_t)GROUPS * 72;

    char* ws = (char*)d_ws;
    u16*   wfrag = (u16*)(ws + 0);          // 32 KB
    u16*   wr1f  = (u16*)(ws + 32768);      // 16 KB
    u16*   wr2f  = (u16*)(ws + 49152);      // 20 KB
    u16*   wc1f  = (u16*)(ws + 69632);      // 4 KB
    float* w1s   = (float*)(ws + 73728);    // 288 B
    float* ces   = (float*)(ws + 74016);    // 24 B

    hipLaunchKernelGGL(prep, dim3(74), dim3(64), 0, stream,
                       W1, a_src1, a_dst1, W2, Wr1, Wr2, Wc1,
                       We1, a_e1, We2, a_e2,
                       wfrag, wr1f, wr2f, wc1f, w1s, ces);

    hipLaunchKernelGGL(gat_fused11, dim3(GROUPS/2), dim3(64), 0, stream,
                       x, ew, W1, b1, a_src2, a_dst2, b2,
                       br1, br2, bc1, Wc2, bc2,
                       wfrag, wr1f, wr2f, wc1f, w1s, ces,
                       recon, cls);
}